// Round 7
// baseline (304.562 us; speedup 1.0000x reference)
//
#include <hip/hip_runtime.h>
#include <math.h>

#define B_SZ 2
#define L_SZ 2048
#define DMODEL 1024
#define DINNER 2048
#define DSTATE 16
#define DCONV 4
#define DTRANK 64

#define CS 32                    // scan chunk size
#define NCH (L_SZ / CS)          // 64 chunks per batch

typedef float f32x4 __attribute__((ext_vector_type(4)));
typedef float f32x2 __attribute__((ext_vector_type(2)));
typedef __bf16 bf16x8 __attribute__((ext_vector_type(8)));

__device__ __forceinline__ float silu_f(float x) {
    return x / (1.0f + __expf(-x));
}

// fast softplus: max(x,0) + log(1+exp(-|x|)); abs err ~1e-6, branch-free tails
__device__ __forceinline__ float softplus_f(float x) {
    return fmaxf(x, 0.0f) + __logf(1.0f + __expf(-fabsf(x)));
}

// raw v_exp_f32: computes 2^x (hardware trans op, no pre-multiply)
__device__ __forceinline__ float fexp2(float x) {
    float r;
    asm("v_exp_f32 %0, %1" : "=v"(r) : "v"(x));
    return r;
}

// fp32 -> bf16 round-to-nearest-even on raw bits
__device__ __forceinline__ unsigned short f2bf(float x) {
    unsigned int u = __float_as_uint(x);
    u = u + 0x7FFFu + ((u >> 16) & 1u);
    return (unsigned short)(u >> 16);
}

__device__ __forceinline__ float bf2f(unsigned short s) {
    return __uint_as_float(((unsigned int)s) << 16);
}

// async global->LDS DMA, 16B per lane; deposits at base + lane*16B.
__device__ __forceinline__ void gload_lds16(const unsigned short* g, unsigned short* l) {
    __builtin_amdgcn_global_load_lds(
        (const __attribute__((address_space(1))) void*)g,
        (__attribute__((address_space(3))) void*)l, 16, 0, 0);
}

union Pack8 { unsigned short s[8]; uint4 v; };

// Transpose + cast: W[R,C] fp32 -> WT[C,R] bf16. Grid (C/32, R/32), 256 thr.
__global__ __launch_bounds__(256) void transpose_cast(
    const float* __restrict__ W, unsigned short* __restrict__ WT, int R, int C)
{
    __shared__ float t[32][33];
    const int tx = threadIdx.x & 31;
    const int ty = threadIdx.x >> 5;
    const int r0 = blockIdx.y * 32;
    const int c0 = blockIdx.x * 32;
    #pragma unroll
    for (int i = 0; i < 4; i++)
        t[ty + i * 8][tx] = W[(r0 + ty + i * 8) * C + c0 + tx];
    __syncthreads();
    #pragma unroll
    for (int i = 0; i < 4; i++)
        WT[(c0 + ty + i * 8) * R + r0 + tx] = f2bf(t[tx][ty + i * 8]);
}

// cast fp32 -> bf16, 8 elems/thread
__global__ __launch_bounds__(256) void cast_bf16(
    const float* __restrict__ src, unsigned short* __restrict__ dst, int n8)
{
    int i = blockIdx.x * 256 + threadIdx.x;
    if (i >= n8) return;
    const float4 f0 = *(const float4*)(src + i * 8);
    const float4 f1 = *(const float4*)(src + i * 8 + 4);
    Pack8 p;
    p.s[0] = f2bf(f0.x); p.s[1] = f2bf(f0.y); p.s[2] = f2bf(f0.z); p.s[3] = f2bf(f0.w);
    p.s[4] = f2bf(f1.x); p.s[5] = f2bf(f1.y); p.s[6] = f2bf(f1.z); p.s[7] = f2bf(f1.w);
    *(uint4*)(dst + i * 8) = p.v;
}

// ---- bf16 MFMA GEMM, B pre-transposed, global_load_lds staging -------------
// (128x128 2-phase kernel, kept for the small GEMMs 3 and 4.)
template <int ACT, int OBF16>
__global__ __launch_bounds__(256) void gemm_bt_lds(
    const unsigned short* __restrict__ A, const unsigned short* __restrict__ BT,
    void* __restrict__ Cout, const float* __restrict__ bias,
    int M, int N, int K, int lda, int ldb, int ldc, int Kc)
{
    __shared__ unsigned short As[128 * 64];
    __shared__ unsigned short Bs[128 * 64];

    const int tid  = threadIdx.x;
    const int lane = tid & 63;
    const int wave = tid >> 6;
    const int wm   = wave >> 1;
    const int wn   = wave & 1;
    const int row0 = blockIdx.y * 128;
    const int col0 = blockIdx.x * 128;
    const int lq   = lane >> 4;
    const int lm   = lane & 15;
    const int kbeg = blockIdx.z * Kc;

    const int rloc = wave * 32 + (lane >> 3);
    const int sc   = (lane & 7) ^ ((lane >> 3) & 7);
    const unsigned short* gA = A + (size_t)(row0 + rloc) * lda + sc * 8;
    const unsigned short* gBp[4];
    #pragma unroll
    for (int is = 0; is < 4; is++) {
        int br = col0 + rloc + 8 * is;
        if (br > N - 1) br = N - 1;
        gBp[is] = BT + (size_t)br * ldb + sc * 8;
    }
    unsigned short* lA = As + wave * 2048;
    unsigned short* lB = Bs + wave * 2048;

    f32x4 acc[4][4];
    #pragma unroll
    for (int i = 0; i < 4; i++)
        #pragma unroll
        for (int j = 0; j < 4; j++)
            #pragma unroll
            for (int r = 0; r < 4; r++) acc[i][j][r] = 0.0f;

    for (int k0 = kbeg; k0 < kbeg + Kc; k0 += 64) {
        #pragma unroll
        for (int is = 0; is < 4; is++) {
            gload_lds16(gA + (size_t)(8 * is) * lda + k0, lA + is * 512);
            gload_lds16(gBp[is] + k0, lB + is * 512);
        }
        __syncthreads();

        #pragma unroll
        for (int ks = 0; ks < 2; ks++) {
            bf16x8 af[4], bfr[4];
            #pragma unroll
            for (int i = 0; i < 4; i++) {
                int row = wm * 64 + i * 16 + lm;
                af[i] = *(const bf16x8*)&As[row * 64 + (((ks * 4 + lq) ^ (row & 7)) * 8)];
            }
            #pragma unroll
            for (int j = 0; j < 4; j++) {
                int row = wn * 64 + j * 16 + lm;
                bfr[j] = *(const bf16x8*)&Bs[row * 64 + (((ks * 4 + lq) ^ (row & 7)) * 8)];
            }
            #pragma unroll
            for (int i = 0; i < 4; i++)
                #pragma unroll
                for (int j = 0; j < 4; j++)
                    acc[i][j] = __builtin_amdgcn_mfma_f32_16x16x32_bf16(
                        af[i], bfr[j], acc[i][j], 0, 0, 0);
        }
        __syncthreads();
    }

    // epilogue: C/D layout col=lane&15, row=(lane>>4)*4+reg
    #pragma unroll
    for (int i = 0; i < 4; i++) {
        #pragma unroll
        for (int r = 0; r < 4; r++) {
            int row = row0 + wm * 64 + i * 16 + lq * 4 + r;
            #pragma unroll
            for (int j = 0; j < 4; j++) {
                int col = col0 + wn * 64 + j * 16 + lm;
                if (col < N) {
                    float v = acc[i][j][r];
                    if (ACT == 1) v = softplus_f(v + bias[col]);
                    if (OBF16) {
                        unsigned short* Cz = (unsigned short*)Cout +
                            (size_t)blockIdx.z * (size_t)M * ldc;
                        Cz[(size_t)row * ldc + col] = f2bf(v);
                    } else {
                        float* Cz = (float*)Cout +
                            (size_t)blockIdx.z * (size_t)M * ldc;
                        Cz[(size_t)row * ldc + col] = v;
                    }
                }
            }
        }
    }
}

// ---- 256x256 8-phase bf16 GEMM, m201-faithful mid-phase barrier (v3) -------
// 512 thr = 8 waves (2M x 4N), per-wave 128x64 out, BK=64, NT = Kc/64 K-tiles.
// LDS 128KB: sm[buf][A|B][unit:4][64x64 bf16]. XOR-swizzled (rule #21).
// v3 phase structure (the m201 pattern): each phase issues ITS OWN ds_reads,
// then STAGE, then a BARRIER sits between the reads and lgkmcnt(0)+MFMA —
// the read latency drains during the barrier wait / other waves' MFMA.
// Tile edge: counted vmcnt(4) + barrier (vmcnt(0) only at last tile).
// Staging calendar per tile t (2 units/phase):
//   q0: (t+1).a1,a3   q1: (t+1).b2,b3   q2: (t+2).b0,b1   q3: (t+2).a0,a2
// Safety: q2 reads a-units (a1/a3 rows) vs stages b0/b1 (disjoint); q3 reads
// a1/a3 vs stages a0/a2 (disjoint); a0/a2 last read q1, staged q3 (2 barriers
// later); b-units last read q0, staged q2 (2 barriers later); vmcnt(4)+edge
// barrier publishes tile t's units before q0's reads.
template <int OBF16>
__global__ __launch_bounds__(512, 2) void gemm_8ph(
    const unsigned short* __restrict__ A, const unsigned short* __restrict__ BT,
    void* __restrict__ Cout, int M, int N, int lda, int ldb, int ldc, int Kc)
{
    __shared__ unsigned short sm[2][2][4][64 * 64];

    const int tid  = threadIdx.x;
    const int lane = tid & 63;
    const int wave = tid >> 6;         // 0..7
    const int wm   = wave >> 2;        // 0..1  (128-row half)
    const int wn   = wave & 3;         // 0..3  (64-col quarter)
    const int lq   = lane >> 4;
    const int lm   = lane & 15;

    // bijective XCD swizzle (gridDim.x % 8 == 0 guaranteed by caller)
    const int cpx = gridDim.x >> 3;
    const int ti  = (blockIdx.x & 7) * cpx + (blockIdx.x >> 3);
    const int nbx = N >> 8;
    const int row0 = (ti / nbx) * 256;
    const int col0 = (ti % nbx) * 256;
    const int kbeg = blockIdx.z * Kc;

    // staging: one gload per thread per 64-row unit (512 thr x 16B = 8KB)
    const int r  = tid >> 3;                 // row within unit, 0..63
    const int sc = (tid & 7) ^ (r & 7);      // pre-swizzled source group
    const unsigned short* gA = A + (size_t)(row0 + r) * lda + sc * 8 + kbeg;
    const unsigned short* gB[4];
    #pragma unroll
    for (int u = 0; u < 4; u++) {
        int br = col0 + u * 64 + r;
        if (br > N - 1) br = N - 1;
        gB[u] = BT + (size_t)br * ldb + sc * 8 + kbeg;
    }

    #define STA(bsel, u, kk) gload_lds16(gA + (size_t)((u) * 64) * lda + (kk), \
                                         &sm[bsel][0][u][wave * 512])
    #define STB(bsel, u, kk) gload_lds16(gB[u] + (kk), &sm[bsel][1][u][wave * 512])

    // LDS-read macros. RDA: A i-pair (2*pr, 2*pr+1) from buffer bsel.
    #define RDA(bsel, pr) { \
        _Pragma("unroll") \
        for (int ii = 0; ii < 2; ii++) { \
            int br = wm * 128 + ((pr) * 2 + ii) * 16 + lm; \
            _Pragma("unroll") \
            for (int ks = 0; ks < 2; ks++) \
                af[ii][ks] = *(const bf16x8*)&sm[bsel][0][br >> 6] \
                    [(br & 63) * 64 + (((ks * 4 + lq) ^ (br & 7)) * 8)]; \
        } }
    #define RDB(bsel) { \
        _Pragma("unroll") \
        for (int j = 0; j < 4; j++) { \
            int br = wn * 64 + j * 16 + lm; \
            _Pragma("unroll") \
            for (int ks = 0; ks < 2; ks++) \
                bq[j][ks] = *(const bf16x8*)&sm[bsel][1][br >> 6] \
                    [(br & 63) * 64 + (((ks * 4 + lq) ^ (br & 7)) * 8)]; \
        } }
    #define MIDBAR() { \
        __builtin_amdgcn_sched_barrier(0); \
        __builtin_amdgcn_s_barrier(); \
        asm volatile("s_waitcnt lgkmcnt(0)" ::: "memory"); \
        __builtin_amdgcn_sched_barrier(0); }
    #define MMPH(p) { \
        __builtin_amdgcn_s_setprio(1); \
        _Pragma("unroll") \
        for (int ii = 0; ii < 2; ii++) \
            _Pragma("unroll") \
            for (int j = 0; j < 4; j++) { \
                acc[2 * (p) + ii][j] = __builtin_amdgcn_mfma_f32_16x16x32_bf16( \
                    af[ii][0], bq[j][0], acc[2 * (p) + ii][j], 0, 0, 0); \
                acc[2 * (p) + ii][j] = __builtin_amdgcn_mfma_f32_16x16x32_bf16( \
                    af[ii][1], bq[j][1], acc[2 * (p) + ii][j], 0, 0, 0); \
            } \
        __builtin_amdgcn_s_setprio(0); \
        __builtin_amdgcn_sched_barrier(0); }

    f32x4 acc[8][4];
    #pragma unroll
    for (int i = 0; i < 8; i++)
        #pragma unroll
        for (int j = 0; j < 4; j++)
            #pragma unroll
            for (int rr = 0; rr < 4; rr++) acc[i][j][rr] = 0.0f;

    const int NT = Kc >> 6;
    // prologue, exact issue order (oldest->newest) matched to vmcnt(4) math:
    // [0.b0 0.b1][0.a0 0.a2][0.a1 0.a3][0.b2 0.b3][1.b0 1.b1][1.a0 1.a2]
    STB(0, 0, 0); STB(0, 1, 0); STA(0, 0, 0); STA(0, 2, 0);
    STA(0, 1, 0); STA(0, 3, 0); STB(0, 2, 0); STB(0, 3, 0);
    if (NT > 1) { STB(1, 0, 64); STB(1, 1, 64); STA(1, 0, 64); STA(1, 2, 64); }

    bf16x8 bq[4][2], af[2][2];

    for (int t = 0; t < NT; ++t) {
        const int b   = t & 1;
        const int kk1 = (t + 1) * 64;
        const int kk2 = (t + 2) * 64;

        // tile edge: publish tile t's 8 staged units
        if (t == NT - 1) asm volatile("s_waitcnt vmcnt(0)" ::: "memory");
        else             asm volatile("s_waitcnt vmcnt(4)" ::: "memory");
        __builtin_amdgcn_s_barrier();
        __builtin_amdgcn_sched_barrier(0);

        // ---- phase 0
        RDB(b); RDA(b, 0);
        if (t + 1 < NT) { STA(b ^ 1, 1, kk1); STA(b ^ 1, 3, kk1); }
        MIDBAR();
        MMPH(0);

        // ---- phase 1
        RDA(b, 1);
        if (t + 1 < NT) { STB(b ^ 1, 2, kk1); STB(b ^ 1, 3, kk1); }
        MIDBAR();
        MMPH(1);

        // ---- phase 2
        RDA(b, 2);
        if (t + 2 < NT) { STB(b, 0, kk2); STB(b, 1, kk2); }
        MIDBAR();
        MMPH(2);

        // ---- phase 3
        RDA(b, 3);
        if (t + 2 < NT) { STA(b, 0, kk2); STA(b, 2, kk2); }
        MIDBAR();
        MMPH(3);
    }
    #undef STA
    #undef STB
    #undef RDA
    #undef RDB
    #undef MIDBAR
    #undef MMPH

    // epilogue: C/D layout col=lane&15, row=(lane>>4)*4+reg
    const size_t zoff = (size_t)blockIdx.z * (size_t)M * ldc;
    #pragma unroll
    for (int i = 0; i < 8; i++) {
        #pragma unroll
        for (int rr = 0; rr < 4; rr++) {
            int row = row0 + wm * 128 + i * 16 + lq * 4 + rr;
            #pragma unroll
            for (int j = 0; j < 4; j++) {
                int col = col0 + wn * 64 + j * 16 + lm;
                if (col < N) {
                    float v = acc[i][j][rr];
                    if (OBF16)
                        ((unsigned short*)Cout)[(size_t)row * ldc + col] = f2bf(v);
                    else
                        ((float*)Cout)[zoff + (size_t)row * ldc + col] = v;
                }
            }
        }
    }
}

// Sum nsplit partial C buffers; also emit bf16 copy of cols<64 (dt_lo).
__global__ __launch_bounds__(256) void reduce_splitk(
    const float* __restrict__ part, float* __restrict__ C,
    unsigned short* __restrict__ dtlo16, int n, int nsplit)
{
    int i = blockIdx.x * 256 + threadIdx.x;
    if (i >= n) return;
    float s = 0.0f;
    for (int z = 0; z < nsplit; z++) s += part[(size_t)z * n + i];
    C[i] = s;
    int row = i / 96;
    int col = i - row * 96;
    if (col < DTRANK) dtlo16[row * DTRANK + col] = f2bf(s);
}

// Sum 4 fp32 partials, vectorized. n4 = total_floats/4.
__global__ __launch_bounds__(256) void reduce4(
    const float* __restrict__ part, float* __restrict__ out, int n4)
{
    int i = blockIdx.x * 256 + threadIdx.x;
    if (i >= n4) return;
    const f32x4* p = (const f32x4*)part;
    f32x4 s = p[i];
    s += p[i + n4];
    s += p[i + 2 * n4];
    s += p[i + 3 * n4];
    ((f32x4*)out)[i] = s;
}

// conv + silu, register-rolling window along l. Reads bf16 xz (cols 0..2048),
// emits bf16 xc16. grid (8, 64, 2).
__global__ __launch_bounds__(256) void conv_silu_v2(
    const unsigned short* __restrict__ xz16, const float* __restrict__ conv_w,
    const float* __restrict__ conv_b, unsigned short* __restrict__ xc16)
{
    const int tid = threadIdx.x;
    const int d   = blockIdx.x * 256 + tid;
    const int l0  = blockIdx.y * 32;
    const int b   = blockIdx.z;
    const float4 w  = *(const float4*)(conv_w + d * 4);
    const float bias = conv_b[d];
    const int t0 = b * L_SZ + l0;
    const unsigned short* src = xz16 + (size_t)t0 * 4096 + d;

    float r0, r1, r2;
    if (l0 == 0) {
        r0 = r1 = r2 = 0.0f;
    } else {
        r0 = bf2f(src[-3 * 4096]);
        r1 = bf2f(src[-2 * 4096]);
        r2 = bf2f(src[-1 * 4096]);
    }
    #pragma unroll 4
    for (int l = 0; l < 32; l++) {
        float r3 = bf2f(src[(size_t)l * 4096]);
        float acc = bias + r0 * w.x + r1 * w.y + r2 * w.z + r3 * w.w;
        xc16[(size_t)(t0 + l) * DINNER + d] = f2bf(silu_f(acc));
        r0 = r1; r1 = r2; r2 = r3;
    }
}

// ---- Chunked parallel selective scan (CS=32, 1024 blocks) -------------------
// v4: 16 states/thread, packed f32x2 math, fexp2 with folded log2e.
// grid: B * NCH * 8 = 1024; db=blk&7, c=(blk>>3)&63, b=blk>>9.
__global__ __launch_bounds__(256) void scan_pass1(
    const unsigned short* __restrict__ xc16, const float* __restrict__ delta,
    const float* __restrict__ dbc, const float* __restrict__ A_log,
    float* __restrict__ P, float* __restrict__ E)
{
    __shared__ float Bs[CS * DSTATE];
    const int tid = threadIdx.x;
    const int db  = blockIdx.x & 7;
    const int c   = (blockIdx.x >> 3) & (NCH - 1);
    const int b   = blockIdx.x >> 9;
    const int d   = db * 256 + tid;
    const int t0  = b * L_SZ + c * CS;

    for (int idx = tid; idx < CS * DSTATE; idx += 256) {
        int step = idx >> 4, i = idx & 15;
        Bs[idx] = dbc[(t0 + step) * 96 + DTRANK + i];
    }

    f32x2 A2v[8], Er2[8];
    const float* Ap = A_log + d * DSTATE;
    #pragma unroll
    for (int p = 0; p < 8; p++) {
        A2v[p].x = -1.44269504f * __expf(Ap[2 * p]);
        A2v[p].y = -1.44269504f * __expf(Ap[2 * p + 1]);
        Er2[p].x = 0.0f; Er2[p].y = 0.0f;
    }
    float sd = 0.0f;

    const float* dp = delta + (size_t)t0 * DINNER + d;
    const unsigned short* up = xc16 + (size_t)t0 * DINNER + d;

    float dv[4], uv[4];
    #pragma unroll
    for (int q = 0; q < 4; q++) {
        dv[q] = dp[(size_t)q * DINNER];
        uv[q] = bf2f(up[(size_t)q * DINNER]);
    }
    __syncthreads();

    for (int lo = 0; lo < CS; lo += 4) {
        float nd[4], nu[4];
        if (lo + 4 < CS) {
            #pragma unroll
            for (int q = 0; q < 4; q++) {
                nd[q] = dp[(size_t)(lo + 4 + q) * DINNER];
                nu[q] = bf2f(up[(size_t)(lo + 4 + q) * DINNER]);
            }
        }
        #pragma unroll
        for (int q = 0; q < 4; q++) {
            const float dvq = dv[q];
            const float du  = dvq * uv[q];
            sd += dvq;
            const f32x4* Bv = (const f32x4*)&Bs[(lo + q) * DSTATE];
            f32x4 b0 = Bv[0], b1 = Bv[1], b2 = Bv[2], b3 = Bv[3];
            #define P1PAIR(p, bb) { \
                f32x2 m = dvq * A2v[p]; \
                f32x2 e; e.x = fexp2(m.x); e.y = fexp2(m.y); \
                Er2[p] = e * Er2[p] + du * (bb); }
            P1PAIR(0, b0.xy) P1PAIR(1, b0.zw)
            P1PAIR(2, b1.xy) P1PAIR(3, b1.zw)
            P1PAIR(4, b2.xy) P1PAIR(5, b2.zw)
            P1PAIR(6, b3.xy) P1PAIR(7, b3.zw)
            #undef P1PAIR
        }
        #pragma unroll
        for (int q = 0; q < 4; q++) { dv[q] = nd[q]; uv[q] = nu[q]; }
    }

    const long long o = ((long long)((b * NCH + c) * DINNER) + d) * DSTATE;
    #pragma unroll
    for (int w = 0; w < 4; w++) {
        f32x4 pv, ev;
        #pragma unroll
        for (int k = 0; k < 2; k++) {
            int p = w * 2 + k;
            pv[2 * k]     = fexp2(A2v[p].x * sd);
            pv[2 * k + 1] = fexp2(A2v[p].y * sd);
            ev[2 * k]     = Er2[p].x;
            ev[2 * k + 1] = Er2[p].y;
        }
        *(f32x4*)(P + o + w * 4) = pv;
        *(f32x4*)(E + o + w * 4) = ev;
    }
}

__global__ __launch_bounds__(256) void scan_pass2(
    const float* __restrict__ P, float* __restrict__ E)
{
    const int gid  = blockIdx.x * 256 + threadIdx.x;
    const int b    = gid >> 15;
    const int rest = gid & 32767;
    float h = 0.0f;
    for (int c = 0; c < NCH; c++) {
        const long long idx = (long long)(b * NCH + c) * (DINNER * DSTATE) + rest;
        float p = P[idx];
        float e = E[idx];
        E[idx] = h;
        h = p * h + e;
    }
}

// pass3 v4: packed math (see pass1), fused silu(z) gate, bf16 y out.
__global__ __launch_bounds__(256) void scan_pass3(
    const unsigned short* __restrict__ xc16, const float* __restrict__ delta,
    const float* __restrict__ dbc, const float* __restrict__ A_log,
    const float* __restrict__ D_skip, const float* __restrict__ Hin,
    const unsigned short* __restrict__ xz16, unsigned short* __restrict__ y16)
{
    __shared__ float BCs[CS * 2 * DSTATE];
    const int tid = threadIdx.x;
    const int db  = blockIdx.x & 7;
    const int c   = (blockIdx.x >> 3) & (NCH - 1);
    const int b   = blockIdx.x >> 9;
    const int d   = db * 256 + tid;
    const int t0  = b * L_SZ + c * CS;

    for (int idx = tid; idx < CS * 2 * DSTATE; idx += 256) {
        int step = idx >> 5, i = idx & 31;
        BCs[idx] = dbc[(t0 + step) * 96 + DTRANK + i];
    }

    f32x2 A2v[8], h2[8];
    const float* Ap = A_log + d * DSTATE;
    const long long o = ((long long)((b * NCH + c) * DINNER) + d) * DSTATE;
    #pragma unroll
    for (int p = 0; p < 8; p++) {
        A2v[p].x = -1.44269504f * __expf(Ap[2 * p]);
        A2v[p].y = -1.44269504f * __expf(Ap[2 * p + 1]);
        h2[p].x = Hin[o + 2 * p];
        h2[p].y = Hin[o + 2 * p + 1];
    }
    const float Dv = D_skip[d];

    const float* dp = delta + (size_t)t0 * DINNER + d;
    const unsigned short* up = xc16 + (size_t)t0 * DINNER + d;
    const unsigned short* zp = xz16 + (size_t)t0 * 4096 + DINNER + d;
    unsigned short* yp = y16 + (size_t)t0 * DINNER + d;

    float dv[4], uv[4], zv[4];
    #pragma unroll
    for (int q = 0; q < 4; q++) {
        dv[q] = dp[(size_t)q * DINNER];
        uv[q] = bf2f(up[(size_t)q * DINNER]);
        zv[q] = bf2f(zp[(size_t)q * 4096]);
    }
    __syncthreads();

    for (int lo = 0; lo < CS; lo += 4) {
        float nd[4], nu[4], nz[4];
        if (lo + 4 < CS) {
            #pragma unroll
            for (int q = 0; q < 4; q++) {
                nd[q] = dp[(size_t)(lo + 4 + q) * DINNER];
                nu[q] = bf2f(up[(size_t)(lo + 4 + q) * DINNER]);
                nz[q] = bf2f(zp[(size_t)(lo + 4 + q) * 4096]);
            }
        }
        #pragma unroll
        for (int q = 0; q < 4; q++) {
            const float dvq = dv[q];
            const float uvq = uv[q];
            const float du  = dvq * uvq;
            const f32x4* Bv = (const f32x4*)&BCs[(lo + q) * 32];
            f32x4 b0 = Bv[0], b1 = Bv[1], b2 = Bv[2], b3 = Bv[3];
            f32x4 c0 = Bv[4], c1 = Bv[5], c2 = Bv[6], c3 = Bv[7];
            f32x2 y0; y0.x = 0.0f; y0.y = 0.0f;
            f32x2 y1; y1.x = 0.0f; y1.y = 0.0f;
            #define P3PAIR(p, bb, cc, ya) { \
                f32x2 m = dvq * A2v[p]; \
                f32x2 e; e.x = fexp2(m.x); e.y = fexp2(m.y); \
                h2[p] = e * h2[p] + du * (bb); \
                ya = ya + h2[p] * (cc); }
            P3PAIR(0, b0.xy, c0.xy, y0) P3PAIR(1, b0.zw, c0.zw, y1)
            P3PAIR(2, b1.xy, c1.xy, y0) P3PAIR(3, b1.zw, c1.zw, y1)
            P3PAIR(4, b2.xy, c2.xy, y0) P3PAIR(5, b2.zw, c2.zw, y1)
            P3PAIR(6, b3.xy, c3.xy, y0) P3PAIR(7, b3.zw, c3.zw, y1)
            #undef P3PAIR
            f32x2 ys = y0 + y1;
            float yv = ys.x + ys.y;
            yp[(size_t)(lo + q) * DINNER] = f2bf((uvq * Dv + yv) * silu_f(zv[q]));
        }
        #pragma unroll
        for (int q = 0; q < 4; q++) { dv[q] = nd[q]; uv[q] = nu[q]; zv[q] = nz[q]; }
    }
}

extern "C" void kernel_launch(void* const* d_in, const int* in_sizes, int n_in,
                              void* d_out, int out_size, void* d_ws, size_t ws_size,
                              hipStream_t stream) {
    const float* x       = (const float*)d_in[0];
    const float* W_in    = (const float*)d_in[1];
    const float* conv_w  = (const float*)d_in[2];
    const float* conv_b  = (const float*)d_in[3];
    const float* W_xproj = (const float*)d_in[4];
    const float* W_dt    = (const float*)d_in[5];
    const float* b_dt    = (const float*)d_in[6];
    const float* A_log   = (const float*)d_in[7];
    const float* D_skip  = (const float*)d_in[8];
    const float* W_out   = (const float*)d_in[9];
    float* out = (float*)d_out;

    // workspace layout, float units (141 MB). Aliases (dead-before-reuse):
    //   parts (dead after reduce) shares Pbuf (written at pass1)
    //   x16 (dead after gemm1)    shares yb16 (written at pass3)
    //   parts6 (GEMM6 split-K partials, 64MB) spans delta..Pbuf — all dead
    //   after pass3; GEMM6/reduce4 run after pass3. 16777216 f exactly. ✓
    float* ws = (float*)d_ws;
    unsigned short* xz16   = (unsigned short*)ws;              // [0 .. 8388608) f
    unsigned short* xc16   = (unsigned short*)(ws +  8388608); // [.. 12582912) f
    float* dbc             = ws + 12582912;                    // [.. 12976128) f
    unsigned short* dtlo16 = (unsigned short*)(ws + 12976128); // [.. 13107200) f
    float* delta           = ws + 13107200;                    // [.. 21495808) f
    float* Ebuf            = ws + 21495808;                    // [.. 25690112) f : 2*64*2048*16
    float* Pbuf            = ws + 25690112;                    // [.. 29884416) f : 2*64*2048*16
    float* parts           = Pbuf;                             //   alias, 3145728 f < 4194304 ✓
    float* parts6          = delta;                            //   alias, 4*4096*1024 = 16777216 f ✓
    unsigned short* yb16   = (unsigned short*)(ws + 29884416); // [.. 31981568) f
    unsigned short* x16    = yb16;                             //   alias
    unsigned short* W_inT    = (unsigned short*)(ws + 31981568); // [.. 34078720) f
    unsigned short* W_xprojT = (unsigned short*)(ws + 34078720); // [.. 34177024) f
    unsigned short* W_dtT    = (unsigned short*)(ws + 34177024); // [.. 34242560) f
    unsigned short* W_outT   = (unsigned short*)(ws + 34242560); // [.. 35291136) f

    const int MT = 4096;  // B*L tokens

    transpose_cast<<<dim3(128, 32), 256, 0, stream>>>(W_in,    W_inT,    1024, 4096);
    transpose_cast<<<dim3(  3, 64), 256, 0, stream>>>(W_xproj, W_xprojT, 2048,   96);
    transpose_cast<<<dim3( 64,  2), 256, 0, stream>>>(W_dt,    W_dtT,      64, 2048);
    transpose_cast<<<dim3( 32, 64), 256, 0, stream>>>(W_out,   W_outT,   2048, 1024);
    cast_bf16<<<dim3(2048), 256, 0, stream>>>(x, x16, 524288);

    // 1) xz = x @ W_in              (4096 x 4096, K=1024) -> bf16, 8-phase v3
    gemm_8ph<1><<<dim3(256), 512, 0, stream>>>(
        x16, W_inT, xz16, MT, 4096, 1024, 1024, 4096, 1024);

    // 2) xc16 = silu(causal_dwconv(xin) + b)
    conv_silu_v2<<<dim3(8, 64, 2), 256, 0, stream>>>(xz16, conv_w, conv_b, xc16);

    // 3) dbc = xc @ W_xproj         (4096 x 96, K=2048) — split-K x8
    gemm_bt_lds<0, 0><<<dim3(1, 32, 8), 256, 0, stream>>>(
        xc16, W_xprojT, parts, nullptr, MT, 96, 2048, 2048, 2048, 96, 256);
    reduce_splitk<<<dim3(1536), 256, 0, stream>>>(parts, dbc, dtlo16, MT * 96, 8);

    // 4) delta = softplus(dt_lo @ W_dt + b_dt)  (4096 x 2048, K=64) — fast softplus
    gemm_bt_lds<1, 0><<<dim3(16, 32), 256, 0, stream>>>(
        dtlo16, W_dtT, delta, b_dt, MT, 2048, 64, 64, 64, 2048, 64);

    // 5) chunked selective scan + fused gate (bf16 y out), packed math v4
    scan_pass1<<<dim3(1024), 256, 0, stream>>>(xc16, delta, dbc, A_log, Pbuf, Ebuf);
    scan_pass2<<<dim3(256), 256, 0, stream>>>(Pbuf, Ebuf);
    scan_pass3<<<dim3(1024), 256, 0, stream>>>(xc16, delta, dbc, A_log, D_skip,
                                               Ebuf, xz16, yb16);

    // 6) out = y @ W_out   (4096 x 1024, K=2048) — 8-phase v3, split-K x4
    //    ldb = 2048 (W_outT row stride = K).
    gemm_8ph<0><<<dim3(64, 1, 4), 512, 0, stream>>>(
        yb16, W_outT, parts6, MT, 1024, 2048, 2048, 1024, 512);
    reduce4<<<dim3(4096), 256, 0, stream>>>(parts6, out, MT * 1024 / 4);
}

// Round 8
// 293.096 us; speedup vs baseline: 1.0391x; 1.0391x over previous
//
#include <hip/hip_runtime.h>
#include <math.h>

#define B_SZ 2
#define L_SZ 2048
#define DMODEL 1024
#define DINNER 2048
#define DSTATE 16
#define DCONV 4
#define DTRANK 64

#define CS 32                    // scan chunk size
#define NCH (L_SZ / CS)          // 64 chunks per batch

typedef float f32x4 __attribute__((ext_vector_type(4)));
typedef float f32x2 __attribute__((ext_vector_type(2)));
typedef __bf16 bf16x8 __attribute__((ext_vector_type(8)));

__device__ __forceinline__ float silu_f(float x) {
    return x / (1.0f + __expf(-x));
}

// fast softplus: max(x,0) + log(1+exp(-|x|)); abs err ~1e-6, branch-free tails
__device__ __forceinline__ float softplus_f(float x) {
    return fmaxf(x, 0.0f) + __logf(1.0f + __expf(-fabsf(x)));
}

// raw v_exp_f32: computes 2^x (hardware trans op, no pre-multiply)
__device__ __forceinline__ float fexp2(float x) {
    float r;
    asm("v_exp_f32 %0, %1" : "=v"(r) : "v"(x));
    return r;
}

// fp32 -> bf16 round-to-nearest-even on raw bits
__device__ __forceinline__ unsigned short f2bf(float x) {
    unsigned int u = __float_as_uint(x);
    u = u + 0x7FFFu + ((u >> 16) & 1u);
    return (unsigned short)(u >> 16);
}

__device__ __forceinline__ float bf2f(unsigned short s) {
    return __uint_as_float(((unsigned int)s) << 16);
}

// async global->LDS DMA, 16B per lane; deposits at base + lane*16B.
__device__ __forceinline__ void gload_lds16(const unsigned short* g, unsigned short* l) {
    __builtin_amdgcn_global_load_lds(
        (const __attribute__((address_space(1))) void*)g,
        (__attribute__((address_space(3))) void*)l, 16, 0, 0);
}

union Pack8 { unsigned short s[8]; uint4 v; };

// Transpose + cast: W[R,C] fp32 -> WT[C,R] bf16. Grid (C/32, R/32), 256 thr.
__global__ __launch_bounds__(256) void transpose_cast(
    const float* __restrict__ W, unsigned short* __restrict__ WT, int R, int C)
{
    __shared__ float t[32][33];
    const int tx = threadIdx.x & 31;
    const int ty = threadIdx.x >> 5;
    const int r0 = blockIdx.y * 32;
    const int c0 = blockIdx.x * 32;
    #pragma unroll
    for (int i = 0; i < 4; i++)
        t[ty + i * 8][tx] = W[(r0 + ty + i * 8) * C + c0 + tx];
    __syncthreads();
    #pragma unroll
    for (int i = 0; i < 4; i++)
        WT[(c0 + ty + i * 8) * R + r0 + tx] = f2bf(t[tx][ty + i * 8]);
}

// cast fp32 -> bf16, 8 elems/thread
__global__ __launch_bounds__(256) void cast_bf16(
    const float* __restrict__ src, unsigned short* __restrict__ dst, int n8)
{
    int i = blockIdx.x * 256 + threadIdx.x;
    if (i >= n8) return;
    const float4 f0 = *(const float4*)(src + i * 8);
    const float4 f1 = *(const float4*)(src + i * 8 + 4);
    Pack8 p;
    p.s[0] = f2bf(f0.x); p.s[1] = f2bf(f0.y); p.s[2] = f2bf(f0.z); p.s[3] = f2bf(f0.w);
    p.s[4] = f2bf(f1.x); p.s[5] = f2bf(f1.y); p.s[6] = f2bf(f1.z); p.s[7] = f2bf(f1.w);
    *(uint4*)(dst + i * 8) = p.v;
}

// ---- bf16 MFMA GEMM, B pre-transposed, global_load_lds staging -------------
// (128x128 2-phase kernel, kept for the small GEMMs 3 and 4.)
template <int ACT, int OBF16>
__global__ __launch_bounds__(256) void gemm_bt_lds(
    const unsigned short* __restrict__ A, const unsigned short* __restrict__ BT,
    void* __restrict__ Cout, const float* __restrict__ bias,
    int M, int N, int K, int lda, int ldb, int ldc, int Kc)
{
    __shared__ unsigned short As[128 * 64];
    __shared__ unsigned short Bs[128 * 64];

    const int tid  = threadIdx.x;
    const int lane = tid & 63;
    const int wave = tid >> 6;
    const int wm   = wave >> 1;
    const int wn   = wave & 1;
    const int row0 = blockIdx.y * 128;
    const int col0 = blockIdx.x * 128;
    const int lq   = lane >> 4;
    const int lm   = lane & 15;
    const int kbeg = blockIdx.z * Kc;

    const int rloc = wave * 32 + (lane >> 3);
    const int sc   = (lane & 7) ^ ((lane >> 3) & 7);
    const unsigned short* gA = A + (size_t)(row0 + rloc) * lda + sc * 8;
    const unsigned short* gBp[4];
    #pragma unroll
    for (int is = 0; is < 4; is++) {
        int br = col0 + rloc + 8 * is;
        if (br > N - 1) br = N - 1;
        gBp[is] = BT + (size_t)br * ldb + sc * 8;
    }
    unsigned short* lA = As + wave * 2048;
    unsigned short* lB = Bs + wave * 2048;

    f32x4 acc[4][4];
    #pragma unroll
    for (int i = 0; i < 4; i++)
        #pragma unroll
        for (int j = 0; j < 4; j++)
            #pragma unroll
            for (int r = 0; r < 4; r++) acc[i][j][r] = 0.0f;

    for (int k0 = kbeg; k0 < kbeg + Kc; k0 += 64) {
        #pragma unroll
        for (int is = 0; is < 4; is++) {
            gload_lds16(gA + (size_t)(8 * is) * lda + k0, lA + is * 512);
            gload_lds16(gBp[is] + k0, lB + is * 512);
        }
        __syncthreads();

        #pragma unroll
        for (int ks = 0; ks < 2; ks++) {
            bf16x8 af[4], bfr[4];
            #pragma unroll
            for (int i = 0; i < 4; i++) {
                int row = wm * 64 + i * 16 + lm;
                af[i] = *(const bf16x8*)&As[row * 64 + (((ks * 4 + lq) ^ (row & 7)) * 8)];
            }
            #pragma unroll
            for (int j = 0; j < 4; j++) {
                int row = wn * 64 + j * 16 + lm;
                bfr[j] = *(const bf16x8*)&Bs[row * 64 + (((ks * 4 + lq) ^ (row & 7)) * 8)];
            }
            #pragma unroll
            for (int i = 0; i < 4; i++)
                #pragma unroll
                for (int j = 0; j < 4; j++)
                    acc[i][j] = __builtin_amdgcn_mfma_f32_16x16x32_bf16(
                        af[i], bfr[j], acc[i][j], 0, 0, 0);
        }
        __syncthreads();
    }

    // epilogue: C/D layout col=lane&15, row=(lane>>4)*4+reg
    #pragma unroll
    for (int i = 0; i < 4; i++) {
        #pragma unroll
        for (int r = 0; r < 4; r++) {
            int row = row0 + wm * 64 + i * 16 + lq * 4 + r;
            #pragma unroll
            for (int j = 0; j < 4; j++) {
                int col = col0 + wn * 64 + j * 16 + lm;
                if (col < N) {
                    float v = acc[i][j][r];
                    if (ACT == 1) v = softplus_f(v + bias[col]);
                    if (OBF16) {
                        unsigned short* Cz = (unsigned short*)Cout +
                            (size_t)blockIdx.z * (size_t)M * ldc;
                        Cz[(size_t)row * ldc + col] = f2bf(v);
                    } else {
                        float* Cz = (float*)Cout +
                            (size_t)blockIdx.z * (size_t)M * ldc;
                        Cz[(size_t)row * ldc + col] = v;
                    }
                }
            }
        }
    }
}

// ---- 256x256 8-phase bf16 GEMM, m201-faithful mid-phase barrier (v3) -------
// OBF16: 0 = fp32 out (with z-offset), 1 = bf16 out (no z-offset),
//        2 = bf16 out with z-offset (split-K bf16 partials).
template <int OBF16>
__global__ __launch_bounds__(512, 2) void gemm_8ph(
    const unsigned short* __restrict__ A, const unsigned short* __restrict__ BT,
    void* __restrict__ Cout, int M, int N, int lda, int ldb, int ldc, int Kc)
{
    __shared__ unsigned short sm[2][2][4][64 * 64];

    const int tid  = threadIdx.x;
    const int lane = tid & 63;
    const int wave = tid >> 6;         // 0..7
    const int wm   = wave >> 2;        // 0..1  (128-row half)
    const int wn   = wave & 3;         // 0..3  (64-col quarter)
    const int lq   = lane >> 4;
    const int lm   = lane & 15;

    // bijective XCD swizzle (gridDim.x % 8 == 0 guaranteed by caller)
    const int cpx = gridDim.x >> 3;
    const int ti  = (blockIdx.x & 7) * cpx + (blockIdx.x >> 3);
    const int nbx = N >> 8;
    const int row0 = (ti / nbx) * 256;
    const int col0 = (ti % nbx) * 256;
    const int kbeg = blockIdx.z * Kc;

    // staging: one gload per thread per 64-row unit (512 thr x 16B = 8KB)
    const int r  = tid >> 3;                 // row within unit, 0..63
    const int sc = (tid & 7) ^ (r & 7);      // pre-swizzled source group
    const unsigned short* gA = A + (size_t)(row0 + r) * lda + sc * 8 + kbeg;
    const unsigned short* gB[4];
    #pragma unroll
    for (int u = 0; u < 4; u++) {
        int br = col0 + u * 64 + r;
        if (br > N - 1) br = N - 1;
        gB[u] = BT + (size_t)br * ldb + sc * 8 + kbeg;
    }

    #define STA(bsel, u, kk) gload_lds16(gA + (size_t)((u) * 64) * lda + (kk), \
                                         &sm[bsel][0][u][wave * 512])
    #define STB(bsel, u, kk) gload_lds16(gB[u] + (kk), &sm[bsel][1][u][wave * 512])

    // LDS-read macros. RDA: A i-pair (2*pr, 2*pr+1) from buffer bsel.
    #define RDA(bsel, pr) { \
        _Pragma("unroll") \
        for (int ii = 0; ii < 2; ii++) { \
            int br = wm * 128 + ((pr) * 2 + ii) * 16 + lm; \
            _Pragma("unroll") \
            for (int ks = 0; ks < 2; ks++) \
                af[ii][ks] = *(const bf16x8*)&sm[bsel][0][br >> 6] \
                    [(br & 63) * 64 + (((ks * 4 + lq) ^ (br & 7)) * 8)]; \
        } }
    #define RDB(bsel) { \
        _Pragma("unroll") \
        for (int j = 0; j < 4; j++) { \
            int br = wn * 64 + j * 16 + lm; \
            _Pragma("unroll") \
            for (int ks = 0; ks < 2; ks++) \
                bq[j][ks] = *(const bf16x8*)&sm[bsel][1][br >> 6] \
                    [(br & 63) * 64 + (((ks * 4 + lq) ^ (br & 7)) * 8)]; \
        } }
    #define MIDBAR() { \
        __builtin_amdgcn_sched_barrier(0); \
        __builtin_amdgcn_s_barrier(); \
        asm volatile("s_waitcnt lgkmcnt(0)" ::: "memory"); \
        __builtin_amdgcn_sched_barrier(0); }
    #define MMPH(p) { \
        __builtin_amdgcn_s_setprio(1); \
        _Pragma("unroll") \
        for (int ii = 0; ii < 2; ii++) \
            _Pragma("unroll") \
            for (int j = 0; j < 4; j++) { \
                acc[2 * (p) + ii][j] = __builtin_amdgcn_mfma_f32_16x16x32_bf16( \
                    af[ii][0], bq[j][0], acc[2 * (p) + ii][j], 0, 0, 0); \
                acc[2 * (p) + ii][j] = __builtin_amdgcn_mfma_f32_16x16x32_bf16( \
                    af[ii][1], bq[j][1], acc[2 * (p) + ii][j], 0, 0, 0); \
            } \
        __builtin_amdgcn_s_setprio(0); \
        __builtin_amdgcn_sched_barrier(0); }

    f32x4 acc[8][4];
    #pragma unroll
    for (int i = 0; i < 8; i++)
        #pragma unroll
        for (int j = 0; j < 4; j++)
            #pragma unroll
            for (int rr = 0; rr < 4; rr++) acc[i][j][rr] = 0.0f;

    const int NT = Kc >> 6;
    // prologue, exact issue order (oldest->newest) matched to vmcnt(4) math:
    // [0.b0 0.b1][0.a0 0.a2][0.a1 0.a3][0.b2 0.b3][1.b0 1.b1][1.a0 1.a2]
    STB(0, 0, 0); STB(0, 1, 0); STA(0, 0, 0); STA(0, 2, 0);
    STA(0, 1, 0); STA(0, 3, 0); STB(0, 2, 0); STB(0, 3, 0);
    if (NT > 1) { STB(1, 0, 64); STB(1, 1, 64); STA(1, 0, 64); STA(1, 2, 64); }

    bf16x8 bq[4][2], af[2][2];

    for (int t = 0; t < NT; ++t) {
        const int b   = t & 1;
        const int kk1 = (t + 1) * 64;
        const int kk2 = (t + 2) * 64;

        // tile edge: publish tile t's 8 staged units
        if (t == NT - 1) asm volatile("s_waitcnt vmcnt(0)" ::: "memory");
        else             asm volatile("s_waitcnt vmcnt(4)" ::: "memory");
        __builtin_amdgcn_s_barrier();
        __builtin_amdgcn_sched_barrier(0);

        // ---- phase 0
        RDB(b); RDA(b, 0);
        if (t + 1 < NT) { STA(b ^ 1, 1, kk1); STA(b ^ 1, 3, kk1); }
        MIDBAR();
        MMPH(0);

        // ---- phase 1
        RDA(b, 1);
        if (t + 1 < NT) { STB(b ^ 1, 2, kk1); STB(b ^ 1, 3, kk1); }
        MIDBAR();
        MMPH(1);

        // ---- phase 2
        RDA(b, 2);
        if (t + 2 < NT) { STB(b, 0, kk2); STB(b, 1, kk2); }
        MIDBAR();
        MMPH(2);

        // ---- phase 3
        RDA(b, 3);
        if (t + 2 < NT) { STA(b, 0, kk2); STA(b, 2, kk2); }
        MIDBAR();
        MMPH(3);
    }
    #undef STA
    #undef STB
    #undef RDA
    #undef RDB
    #undef MIDBAR
    #undef MMPH

    // epilogue: C/D layout col=lane&15, row=(lane>>4)*4+reg
    const size_t zoff = (size_t)blockIdx.z * (size_t)M * ldc;
    #pragma unroll
    for (int i = 0; i < 8; i++) {
        #pragma unroll
        for (int rr = 0; rr < 4; rr++) {
            int row = row0 + wm * 128 + i * 16 + lq * 4 + rr;
            #pragma unroll
            for (int j = 0; j < 4; j++) {
                int col = col0 + wn * 64 + j * 16 + lm;
                if (col < N) {
                    float v = acc[i][j][rr];
                    if (OBF16 == 1)
                        ((unsigned short*)Cout)[(size_t)row * ldc + col] = f2bf(v);
                    else if (OBF16 == 2)
                        ((unsigned short*)Cout)[zoff + (size_t)row * ldc + col] = f2bf(v);
                    else
                        ((float*)Cout)[zoff + (size_t)row * ldc + col] = v;
                }
            }
        }
    }
}

// Sum nsplit partial C buffers; also emit bf16 copy of cols<64 (dt_lo).
__global__ __launch_bounds__(256) void reduce_splitk(
    const float* __restrict__ part, float* __restrict__ C,
    unsigned short* __restrict__ dtlo16, int n, int nsplit)
{
    int i = blockIdx.x * 256 + threadIdx.x;
    if (i >= n) return;
    float s = 0.0f;
    for (int z = 0; z < nsplit; z++) s += part[(size_t)z * n + i];
    C[i] = s;
    int row = i / 96;
    int col = i - row * 96;
    if (col < DTRANK) dtlo16[row * DTRANK + col] = f2bf(s);
}

// Sum 4 bf16 partial planes (plane stride 4096*1024 ushorts), fp32 out.
// 8 elems/thread via uint4; n8 = total/8.
__global__ __launch_bounds__(256) void reduce4b(
    const unsigned short* __restrict__ part, float* __restrict__ out, int n8)
{
    int i = blockIdx.x * 256 + threadIdx.x;
    if (i >= n8) return;
    const uint4* p4 = (const uint4*)part;
    float a0 = 0, a1 = 0, a2 = 0, a3 = 0, a4 = 0, a5 = 0, a6 = 0, a7 = 0;
    #pragma unroll
    for (int z = 0; z < 4; z++) {
        uint4 v = p4[(size_t)z * 524288 + i];   // 4194304 ushorts / 8 per uint4
        a0 += bf2f((unsigned short)(v.x & 0xffff)); a1 += bf2f((unsigned short)(v.x >> 16));
        a2 += bf2f((unsigned short)(v.y & 0xffff)); a3 += bf2f((unsigned short)(v.y >> 16));
        a4 += bf2f((unsigned short)(v.z & 0xffff)); a5 += bf2f((unsigned short)(v.z >> 16));
        a6 += bf2f((unsigned short)(v.w & 0xffff)); a7 += bf2f((unsigned short)(v.w >> 16));
    }
    float4 o0 = {a0, a1, a2, a3};
    float4 o1 = {a4, a5, a6, a7};
    *(float4*)(out + (size_t)i * 8)     = o0;
    *(float4*)(out + (size_t)i * 8 + 4) = o1;
}

// conv + silu, register-rolling window along l. Reads bf16 xz (cols 0..2048),
// emits bf16 xc16. grid (8, 64, 2).
__global__ __launch_bounds__(256) void conv_silu_v2(
    const unsigned short* __restrict__ xz16, const float* __restrict__ conv_w,
    const float* __restrict__ conv_b, unsigned short* __restrict__ xc16)
{
    const int tid = threadIdx.x;
    const int d   = blockIdx.x * 256 + tid;
    const int l0  = blockIdx.y * 32;
    const int b   = blockIdx.z;
    const float4 w  = *(const float4*)(conv_w + d * 4);
    const float bias = conv_b[d];
    const int t0 = b * L_SZ + l0;
    const unsigned short* src = xz16 + (size_t)t0 * 4096 + d;

    float r0, r1, r2;
    if (l0 == 0) {
        r0 = r1 = r2 = 0.0f;
    } else {
        r0 = bf2f(src[-3 * 4096]);
        r1 = bf2f(src[-2 * 4096]);
        r2 = bf2f(src[-1 * 4096]);
    }
    #pragma unroll 4
    for (int l = 0; l < 32; l++) {
        float r3 = bf2f(src[(size_t)l * 4096]);
        float acc = bias + r0 * w.x + r1 * w.y + r2 * w.z + r3 * w.w;
        xc16[(size_t)(t0 + l) * DINNER + d] = f2bf(silu_f(acc));
        r0 = r1; r1 = r2; r2 = r3;
    }
}

// ---- Chunked parallel selective scan (CS=32, 1024 blocks) -------------------
// v5: bf16 delta input (GEMM4 emits bf16). 16 states/thread, packed f32x2
// math, fexp2 with folded log2e.
// grid: B * NCH * 8 = 1024; db=blk&7, c=(blk>>3)&63, b=blk>>9.
__global__ __launch_bounds__(256) void scan_pass1(
    const unsigned short* __restrict__ xc16, const unsigned short* __restrict__ delta16,
    const float* __restrict__ dbc, const float* __restrict__ A_log,
    float* __restrict__ P, float* __restrict__ E)
{
    __shared__ float Bs[CS * DSTATE];
    const int tid = threadIdx.x;
    const int db  = blockIdx.x & 7;
    const int c   = (blockIdx.x >> 3) & (NCH - 1);
    const int b   = blockIdx.x >> 9;
    const int d   = db * 256 + tid;
    const int t0  = b * L_SZ + c * CS;

    for (int idx = tid; idx < CS * DSTATE; idx += 256) {
        int step = idx >> 4, i = idx & 15;
        Bs[idx] = dbc[(t0 + step) * 96 + DTRANK + i];
    }

    f32x2 A2v[8], Er2[8];
    const float* Ap = A_log + d * DSTATE;
    #pragma unroll
    for (int p = 0; p < 8; p++) {
        A2v[p].x = -1.44269504f * __expf(Ap[2 * p]);
        A2v[p].y = -1.44269504f * __expf(Ap[2 * p + 1]);
        Er2[p].x = 0.0f; Er2[p].y = 0.0f;
    }
    float sd = 0.0f;

    const unsigned short* dp = delta16 + (size_t)t0 * DINNER + d;
    const unsigned short* up = xc16 + (size_t)t0 * DINNER + d;

    float dv[4], uv[4];
    #pragma unroll
    for (int q = 0; q < 4; q++) {
        dv[q] = bf2f(dp[(size_t)q * DINNER]);
        uv[q] = bf2f(up[(size_t)q * DINNER]);
    }
    __syncthreads();

    for (int lo = 0; lo < CS; lo += 4) {
        float nd[4], nu[4];
        if (lo + 4 < CS) {
            #pragma unroll
            for (int q = 0; q < 4; q++) {
                nd[q] = bf2f(dp[(size_t)(lo + 4 + q) * DINNER]);
                nu[q] = bf2f(up[(size_t)(lo + 4 + q) * DINNER]);
            }
        }
        #pragma unroll
        for (int q = 0; q < 4; q++) {
            const float dvq = dv[q];
            const float du  = dvq * uv[q];
            sd += dvq;
            const f32x4* Bv = (const f32x4*)&Bs[(lo + q) * DSTATE];
            f32x4 b0 = Bv[0], b1 = Bv[1], b2 = Bv[2], b3 = Bv[3];
            #define P1PAIR(p, bb) { \
                f32x2 m = dvq * A2v[p]; \
                f32x2 e; e.x = fexp2(m.x); e.y = fexp2(m.y); \
                Er2[p] = e * Er2[p] + du * (bb); }
            P1PAIR(0, b0.xy) P1PAIR(1, b0.zw)
            P1PAIR(2, b1.xy) P1PAIR(3, b1.zw)
            P1PAIR(4, b2.xy) P1PAIR(5, b2.zw)
            P1PAIR(6, b3.xy) P1PAIR(7, b3.zw)
            #undef P1PAIR
        }
        #pragma unroll
        for (int q = 0; q < 4; q++) { dv[q] = nd[q]; uv[q] = nu[q]; }
    }

    const long long o = ((long long)((b * NCH + c) * DINNER) + d) * DSTATE;
    #pragma unroll
    for (int w = 0; w < 4; w++) {
        f32x4 pv, ev;
        #pragma unroll
        for (int k = 0; k < 2; k++) {
            int p = w * 2 + k;
            pv[2 * k]     = fexp2(A2v[p].x * sd);
            pv[2 * k + 1] = fexp2(A2v[p].y * sd);
            ev[2 * k]     = Er2[p].x;
            ev[2 * k + 1] = Er2[p].y;
        }
        *(f32x4*)(P + o + w * 4) = pv;
        *(f32x4*)(E + o + w * 4) = ev;
    }
}

__global__ __launch_bounds__(256) void scan_pass2(
    const float* __restrict__ P, float* __restrict__ E)
{
    const int gid  = blockIdx.x * 256 + threadIdx.x;
    const int b    = gid >> 15;
    const int rest = gid & 32767;
    float h = 0.0f;
    for (int c = 0; c < NCH; c++) {
        const long long idx = (long long)(b * NCH + c) * (DINNER * DSTATE) + rest;
        float p = P[idx];
        float e = E[idx];
        E[idx] = h;
        h = p * h + e;
    }
}

// pass3 v5: bf16 delta, packed math, fused silu(z) gate, bf16 y out.
__global__ __launch_bounds__(256) void scan_pass3(
    const unsigned short* __restrict__ xc16, const unsigned short* __restrict__ delta16,
    const float* __restrict__ dbc, const float* __restrict__ A_log,
    const float* __restrict__ D_skip, const float* __restrict__ Hin,
    const unsigned short* __restrict__ xz16, unsigned short* __restrict__ y16)
{
    __shared__ float BCs[CS * 2 * DSTATE];
    const int tid = threadIdx.x;
    const int db  = blockIdx.x & 7;
    const int c   = (blockIdx.x >> 3) & (NCH - 1);
    const int b   = blockIdx.x >> 9;
    const int d   = db * 256 + tid;
    const int t0  = b * L_SZ + c * CS;

    for (int idx = tid; idx < CS * 2 * DSTATE; idx += 256) {
        int step = idx >> 5, i = idx & 31;
        BCs[idx] = dbc[(t0 + step) * 96 + DTRANK + i];
    }

    f32x2 A2v[8], h2[8];
    const float* Ap = A_log + d * DSTATE;
    const long long o = ((long long)((b * NCH + c) * DINNER) + d) * DSTATE;
    #pragma unroll
    for (int p = 0; p < 8; p++) {
        A2v[p].x = -1.44269504f * __expf(Ap[2 * p]);
        A2v[p].y = -1.44269504f * __expf(Ap[2 * p + 1]);
        h2[p].x = Hin[o + 2 * p];
        h2[p].y = Hin[o + 2 * p + 1];
    }
    const float Dv = D_skip[d];

    const unsigned short* dp = delta16 + (size_t)t0 * DINNER + d;
    const unsigned short* up = xc16 + (size_t)t0 * DINNER + d;
    const unsigned short* zp = xz16 + (size_t)t0 * 4096 + DINNER + d;
    unsigned short* yp = y16 + (size_t)t0 * DINNER + d;

    float dv[4], uv[4], zv[4];
    #pragma unroll
    for (int q = 0; q < 4; q++) {
        dv[q] = bf2f(dp[(size_t)q * DINNER]);
        uv[q] = bf2f(up[(size_t)q * DINNER]);
        zv[q] = bf2f(zp[(size_t)q * 4096]);
    }
    __syncthreads();

    for (int lo = 0; lo < CS; lo += 4) {
        float nd[4], nu[4], nz[4];
        if (lo + 4 < CS) {
            #pragma unroll
            for (int q = 0; q < 4; q++) {
                nd[q] = bf2f(dp[(size_t)(lo + 4 + q) * DINNER]);
                nu[q] = bf2f(up[(size_t)(lo + 4 + q) * DINNER]);
                nz[q] = bf2f(zp[(size_t)(lo + 4 + q) * 4096]);
            }
        }
        #pragma unroll
        for (int q = 0; q < 4; q++) {
            const float dvq = dv[q];
            const float uvq = uv[q];
            const float du  = dvq * uvq;
            const f32x4* Bv = (const f32x4*)&BCs[(lo + q) * 32];
            f32x4 b0 = Bv[0], b1 = Bv[1], b2 = Bv[2], b3 = Bv[3];
            f32x4 c0 = Bv[4], c1 = Bv[5], c2 = Bv[6], c3 = Bv[7];
            f32x2 y0; y0.x = 0.0f; y0.y = 0.0f;
            f32x2 y1; y1.x = 0.0f; y1.y = 0.0f;
            #define P3PAIR(p, bb, cc, ya) { \
                f32x2 m = dvq * A2v[p]; \
                f32x2 e; e.x = fexp2(m.x); e.y = fexp2(m.y); \
                h2[p] = e * h2[p] + du * (bb); \
                ya = ya + h2[p] * (cc); }
            P3PAIR(0, b0.xy, c0.xy, y0) P3PAIR(1, b0.zw, c0.zw, y1)
            P3PAIR(2, b1.xy, c1.xy, y0) P3PAIR(3, b1.zw, c1.zw, y1)
            P3PAIR(4, b2.xy, c2.xy, y0) P3PAIR(5, b2.zw, c2.zw, y1)
            P3PAIR(6, b3.xy, c3.xy, y0) P3PAIR(7, b3.zw, c3.zw, y1)
            #undef P3PAIR
            f32x2 ys = y0 + y1;
            float yv = ys.x + ys.y;
            yp[(size_t)(lo + q) * DINNER] = f2bf((uvq * Dv + yv) * silu_f(zv[q]));
        }
        #pragma unroll
        for (int q = 0; q < 4; q++) { dv[q] = nd[q]; uv[q] = nu[q]; zv[q] = nz[q]; }
    }
}

extern "C" void kernel_launch(void* const* d_in, const int* in_sizes, int n_in,
                              void* d_out, int out_size, void* d_ws, size_t ws_size,
                              hipStream_t stream) {
    const float* x       = (const float*)d_in[0];
    const float* W_in    = (const float*)d_in[1];
    const float* conv_w  = (const float*)d_in[2];
    const float* conv_b  = (const float*)d_in[3];
    const float* W_xproj = (const float*)d_in[4];
    const float* W_dt    = (const float*)d_in[5];
    const float* b_dt    = (const float*)d_in[6];
    const float* A_log   = (const float*)d_in[7];
    const float* D_skip  = (const float*)d_in[8];
    const float* W_out   = (const float*)d_in[9];
    float* out = (float*)d_out;

    // workspace layout, float units. Aliases (dead-before-reuse):
    //   parts  (GEMM3 fp32 partials) shares Pbuf (written at pass1)
    //   x16    (dead after gemm1)    shares yb16 (written at pass3)
    //   parts6u (GEMM6 bf16 partials, 16.7M ushorts = 8.4M f) spans
    //   [13107200, 21495808) = delta16 (4.2M f) + freed gap — delta16 dead
    //   after pass3; disjoint from Ebuf which pass3 reads. GEMM6 runs after.
    float* ws = (float*)d_ws;
    unsigned short* xz16   = (unsigned short*)ws;              // [0 .. 8388608) f
    unsigned short* xc16   = (unsigned short*)(ws +  8388608); // [.. 12582912) f
    float* dbc             = ws + 12582912;                    // [.. 12976128) f
    unsigned short* dtlo16 = (unsigned short*)(ws + 12976128); // [.. 13107200) f
    unsigned short* delta16 = (unsigned short*)(ws + 13107200); // [.. 17301504) f (bf16 4096x2048)
    unsigned short* parts6u = (unsigned short*)(ws + 13107200); //  alias, [.. 21495808) f
    float* Ebuf            = ws + 21495808;                    // [.. 25690112) f : 2*64*2048*16
    float* Pbuf            = ws + 25690112;                    // [.. 29884416) f : 2*64*2048*16
    float* parts           = Pbuf;                             //   alias, 3145728 f < 4194304 ✓
    unsigned short* yb16   = (unsigned short*)(ws + 29884416); // [.. 31981568) f
    unsigned short* x16    = yb16;                             //   alias
    unsigned short* W_inT    = (unsigned short*)(ws + 31981568); // [.. 34078720) f
    unsigned short* W_xprojT = (unsigned short*)(ws + 34078720); // [.. 34177024) f
    unsigned short* W_dtT    = (unsigned short*)(ws + 34177024); // [.. 34242560) f
    unsigned short* W_outT   = (unsigned short*)(ws + 34242560); // [.. 35291136) f

    const int MT = 4096;  // B*L tokens

    transpose_cast<<<dim3(128, 32), 256, 0, stream>>>(W_in,    W_inT,    1024, 4096);
    transpose_cast<<<dim3(  3, 64), 256, 0, stream>>>(W_xproj, W_xprojT, 2048,   96);
    transpose_cast<<<dim3( 64,  2), 256, 0, stream>>>(W_dt,    W_dtT,      64, 2048);
    transpose_cast<<<dim3( 32, 64), 256, 0, stream>>>(W_out,   W_outT,   2048, 1024);
    cast_bf16<<<dim3(2048), 256, 0, stream>>>(x, x16, 524288);

    // 1) xz = x @ W_in              (4096 x 4096, K=1024) -> bf16, 8-phase v3
    gemm_8ph<1><<<dim3(256), 512, 0, stream>>>(
        x16, W_inT, xz16, MT, 4096, 1024, 1024, 4096, 1024);

    // 2) xc16 = silu(causal_dwconv(xin) + b)
    conv_silu_v2<<<dim3(8, 64, 2), 256, 0, stream>>>(xz16, conv_w, conv_b, xc16);

    // 3) dbc = xc @ W_xproj         (4096 x 96, K=2048) — split-K x8
    gemm_bt_lds<0, 0><<<dim3(1, 32, 8), 256, 0, stream>>>(
        xc16, W_xprojT, parts, nullptr, MT, 96, 2048, 2048, 2048, 96, 256);
    reduce_splitk<<<dim3(1536), 256, 0, stream>>>(parts, dbc, dtlo16, MT * 96, 8);

    // 4) delta16 = softplus(dt_lo @ W_dt + b_dt)  (4096 x 2048, K=64) -> bf16
    gemm_bt_lds<1, 1><<<dim3(16, 32), 256, 0, stream>>>(
        dtlo16, W_dtT, delta16, b_dt, MT, 2048, 64, 64, 64, 2048, 64);

    // 5) chunked selective scan + fused gate (bf16 y out), bf16 delta v5
    scan_pass1<<<dim3(1024), 256, 0, stream>>>(xc16, delta16, dbc, A_log, Pbuf, Ebuf);
    scan_pass2<<<dim3(256), 256, 0, stream>>>(Pbuf, Ebuf);
    scan_pass3<<<dim3(1024), 256, 0, stream>>>(xc16, delta16, dbc, A_log, D_skip,
                                               Ebuf, xz16, yb16);

    // 6) out = y @ W_out   (4096 x 1024, K=2048) — 8-phase v3, split-K x4,
    //    bf16 partials (OBF16=2), ldb = 2048 (W_outT row stride = K).
    gemm_8ph<2><<<dim3(64, 1, 4), 512, 0, stream>>>(
        yb16, W_outT, parts6u, MT, 1024, 2048, 2048, 1024, 512);
    reduce4b<<<dim3(2048), 256, 0, stream>>>(parts6u, out, MT * 1024 / 8);
}

// Round 9
// 286.253 us; speedup vs baseline: 1.0640x; 1.0239x over previous
//
#include <hip/hip_runtime.h>
#include <math.h>

#define B_SZ 2
#define L_SZ 2048
#define DMODEL 1024
#define DINNER 2048
#define DSTATE 16
#define DCONV 4
#define DTRANK 64

#define CS 32                    // scan chunk size
#define NCH (L_SZ / CS)          // 64 chunks per batch

typedef float f32x4 __attribute__((ext_vector_type(4)));
typedef float f32x2 __attribute__((ext_vector_type(2)));
typedef __bf16 bf16x8 __attribute__((ext_vector_type(8)));

__device__ __forceinline__ float silu_f(float x) {
    return x / (1.0f + __expf(-x));
}

// fast softplus: max(x,0) + log(1+exp(-|x|)); abs err ~1e-6, branch-free tails
__device__ __forceinline__ float softplus_f(float x) {
    return fmaxf(x, 0.0f) + __logf(1.0f + __expf(-fabsf(x)));
}

// raw v_exp_f32: computes 2^x (hardware trans op, no pre-multiply)
__device__ __forceinline__ float fexp2(float x) {
    float r;
    asm("v_exp_f32 %0, %1" : "=v"(r) : "v"(x));
    return r;
}

// fp32 -> bf16 round-to-nearest-even on raw bits
__device__ __forceinline__ unsigned short f2bf(float x) {
    unsigned int u = __float_as_uint(x);
    u = u + 0x7FFFu + ((u >> 16) & 1u);
    return (unsigned short)(u >> 16);
}

__device__ __forceinline__ float bf2f(unsigned short s) {
    return __uint_as_float(((unsigned int)s) << 16);
}

// async global->LDS DMA, 16B per lane; deposits at base + lane*16B.
__device__ __forceinline__ void gload_lds16(const unsigned short* g, unsigned short* l) {
    __builtin_amdgcn_global_load_lds(
        (const __attribute__((address_space(1))) void*)g,
        (__attribute__((address_space(3))) void*)l, 16, 0, 0);
}

union Pack8 { unsigned short s[8]; uint4 v; };

// transpose+cast tile body: W[R,C] fp32 -> WT[C,R] bf16, 32x32 tile (bx,by)
__device__ __forceinline__ void tc_tile(
    const float* __restrict__ W, unsigned short* __restrict__ WT,
    int R, int C, int bx, int by, float (*t)[33])
{
    const int tx = threadIdx.x & 31;
    const int ty = threadIdx.x >> 5;
    const int r0 = by * 32;
    const int c0 = bx * 32;
    #pragma unroll
    for (int i = 0; i < 4; i++)
        t[ty + i * 8][tx] = W[(size_t)(r0 + ty + i * 8) * C + c0 + tx];
    __syncthreads();
    #pragma unroll
    for (int i = 0; i < 4; i++)
        WT[(size_t)(c0 + ty + i * 8) * R + r0 + tx] = f2bf(t[tx][ty + i * 8]);
}

// ONE prep kernel: all 4 weight transposes + x cast. 1D grid, range dispatch.
// blocks: [0,4096) W_in | [4096,4288) W_xproj | [4288,4416) W_dt |
//         [4416,6464) W_out | [6464,8512) cast x (2048 blocks)
__global__ __launch_bounds__(256) void prep_all(
    const float* __restrict__ W_in,    unsigned short* __restrict__ W_inT,
    const float* __restrict__ W_xproj, unsigned short* __restrict__ W_xprojT,
    const float* __restrict__ W_dt,    unsigned short* __restrict__ W_dtT,
    const float* __restrict__ W_out,   unsigned short* __restrict__ W_outT,
    const float* __restrict__ x,       unsigned short* __restrict__ x16)
{
    __shared__ float t[32][33];
    int b = blockIdx.x;
    if (b < 4096) { tc_tile(W_in, W_inT, 1024, 4096, b % 128, b / 128, t); return; }
    b -= 4096;
    if (b < 192)  { tc_tile(W_xproj, W_xprojT, 2048, 96, b % 3, b / 3, t); return; }
    b -= 192;
    if (b < 128)  { tc_tile(W_dt, W_dtT, 64, 2048, b % 64, b / 64, t); return; }
    b -= 128;
    if (b < 2048) { tc_tile(W_out, W_outT, 2048, 1024, b % 32, b / 32, t); return; }
    b -= 2048;
    // cast x -> bf16, 8 elems/thread (2048 blocks x 256 thr x 8 = 4194304)
    int i = b * 256 + threadIdx.x;
    const float4 f0 = *(const float4*)(x + (size_t)i * 8);
    const float4 f1 = *(const float4*)(x + (size_t)i * 8 + 4);
    Pack8 p;
    p.s[0] = f2bf(f0.x); p.s[1] = f2bf(f0.y); p.s[2] = f2bf(f0.z); p.s[3] = f2bf(f0.w);
    p.s[4] = f2bf(f1.x); p.s[5] = f2bf(f1.y); p.s[6] = f2bf(f1.z); p.s[7] = f2bf(f1.w);
    *(uint4*)(x16 + (size_t)i * 8) = p.v;
}

// ---- bf16 MFMA GEMM, B pre-transposed, global_load_lds staging -------------
// (128x128 2-phase kernel, kept for the small GEMMs 3 and 4.)
// OBF16=1 writes bf16 (with z-plane offset), 0 writes fp32 (with z-plane).
template <int ACT, int OBF16>
__global__ __launch_bounds__(256) void gemm_bt_lds(
    const unsigned short* __restrict__ A, const unsigned short* __restrict__ BT,
    void* __restrict__ Cout, const float* __restrict__ bias,
    int M, int N, int K, int lda, int ldb, int ldc, int Kc)
{
    __shared__ unsigned short As[128 * 64];
    __shared__ unsigned short Bs[128 * 64];

    const int tid  = threadIdx.x;
    const int lane = tid & 63;
    const int wave = tid >> 6;
    const int wm   = wave >> 1;
    const int wn   = wave & 1;
    const int row0 = blockIdx.y * 128;
    const int col0 = blockIdx.x * 128;
    const int lq   = lane >> 4;
    const int lm   = lane & 15;
    const int kbeg = blockIdx.z * Kc;

    const int rloc = wave * 32 + (lane >> 3);
    const int sc   = (lane & 7) ^ ((lane >> 3) & 7);
    const unsigned short* gA = A + (size_t)(row0 + rloc) * lda + sc * 8;
    const unsigned short* gBp[4];
    #pragma unroll
    for (int is = 0; is < 4; is++) {
        int br = col0 + rloc + 8 * is;
        if (br > N - 1) br = N - 1;
        gBp[is] = BT + (size_t)br * ldb + sc * 8;
    }
    unsigned short* lA = As + wave * 2048;
    unsigned short* lB = Bs + wave * 2048;

    f32x4 acc[4][4];
    #pragma unroll
    for (int i = 0; i < 4; i++)
        #pragma unroll
        for (int j = 0; j < 4; j++)
            #pragma unroll
            for (int r = 0; r < 4; r++) acc[i][j][r] = 0.0f;

    for (int k0 = kbeg; k0 < kbeg + Kc; k0 += 64) {
        #pragma unroll
        for (int is = 0; is < 4; is++) {
            gload_lds16(gA + (size_t)(8 * is) * lda + k0, lA + is * 512);
            gload_lds16(gBp[is] + k0, lB + is * 512);
        }
        __syncthreads();

        #pragma unroll
        for (int ks = 0; ks < 2; ks++) {
            bf16x8 af[4], bfr[4];
            #pragma unroll
            for (int i = 0; i < 4; i++) {
                int row = wm * 64 + i * 16 + lm;
                af[i] = *(const bf16x8*)&As[row * 64 + (((ks * 4 + lq) ^ (row & 7)) * 8)];
            }
            #pragma unroll
            for (int j = 0; j < 4; j++) {
                int row = wn * 64 + j * 16 + lm;
                bfr[j] = *(const bf16x8*)&Bs[row * 64 + (((ks * 4 + lq) ^ (row & 7)) * 8)];
            }
            #pragma unroll
            for (int i = 0; i < 4; i++)
                #pragma unroll
                for (int j = 0; j < 4; j++)
                    acc[i][j] = __builtin_amdgcn_mfma_f32_16x16x32_bf16(
                        af[i], bfr[j], acc[i][j], 0, 0, 0);
        }
        __syncthreads();
    }

    // epilogue: C/D layout col=lane&15, row=(lane>>4)*4+reg
    #pragma unroll
    for (int i = 0; i < 4; i++) {
        #pragma unroll
        for (int r = 0; r < 4; r++) {
            int row = row0 + wm * 64 + i * 16 + lq * 4 + r;
            #pragma unroll
            for (int j = 0; j < 4; j++) {
                int col = col0 + wn * 64 + j * 16 + lm;
                if (col < N) {
                    float v = acc[i][j][r];
                    if (ACT == 1) v = softplus_f(v + bias[col]);
                    if (OBF16) {
                        unsigned short* Cz = (unsigned short*)Cout +
                            (size_t)blockIdx.z * (size_t)M * ldc;
                        Cz[(size_t)row * ldc + col] = f2bf(v);
                    } else {
                        float* Cz = (float*)Cout +
                            (size_t)blockIdx.z * (size_t)M * ldc;
                        Cz[(size_t)row * ldc + col] = v;
                    }
                }
            }
        }
    }
}

// ---- 256x256 8-phase bf16 GEMM, m201-faithful mid-phase barrier (v3) -------
// OBF16: 0 = fp32 out (with z-offset), 1 = bf16 out (no z-offset),
//        2 = bf16 out with z-offset (split-K bf16 partials).
template <int OBF16>
__global__ __launch_bounds__(512, 2) void gemm_8ph(
    const unsigned short* __restrict__ A, const unsigned short* __restrict__ BT,
    void* __restrict__ Cout, int M, int N, int lda, int ldb, int ldc, int Kc)
{
    __shared__ unsigned short sm[2][2][4][64 * 64];

    const int tid  = threadIdx.x;
    const int lane = tid & 63;
    const int wave = tid >> 6;         // 0..7
    const int wm   = wave >> 2;        // 0..1  (128-row half)
    const int wn   = wave & 3;         // 0..3  (64-col quarter)
    const int lq   = lane >> 4;
    const int lm   = lane & 15;

    // bijective XCD swizzle (gridDim.x % 8 == 0 guaranteed by caller)
    const int cpx = gridDim.x >> 3;
    const int ti  = (blockIdx.x & 7) * cpx + (blockIdx.x >> 3);
    const int nbx = N >> 8;
    const int row0 = (ti / nbx) * 256;
    const int col0 = (ti % nbx) * 256;
    const int kbeg = blockIdx.z * Kc;

    // staging: one gload per thread per 64-row unit (512 thr x 16B = 8KB)
    const int r  = tid >> 3;                 // row within unit, 0..63
    const int sc = (tid & 7) ^ (r & 7);      // pre-swizzled source group
    const unsigned short* gA = A + (size_t)(row0 + r) * lda + sc * 8 + kbeg;
    const unsigned short* gB[4];
    #pragma unroll
    for (int u = 0; u < 4; u++) {
        int br = col0 + u * 64 + r;
        if (br > N - 1) br = N - 1;
        gB[u] = BT + (size_t)br * ldb + sc * 8 + kbeg;
    }

    #define STA(bsel, u, kk) gload_lds16(gA + (size_t)((u) * 64) * lda + (kk), \
                                         &sm[bsel][0][u][wave * 512])
    #define STB(bsel, u, kk) gload_lds16(gB[u] + (kk), &sm[bsel][1][u][wave * 512])

    // LDS-read macros. RDA: A i-pair (2*pr, 2*pr+1) from buffer bsel.
    #define RDA(bsel, pr) { \
        _Pragma("unroll") \
        for (int ii = 0; ii < 2; ii++) { \
            int br = wm * 128 + ((pr) * 2 + ii) * 16 + lm; \
            _Pragma("unroll") \
            for (int ks = 0; ks < 2; ks++) \
                af[ii][ks] = *(const bf16x8*)&sm[bsel][0][br >> 6] \
                    [(br & 63) * 64 + (((ks * 4 + lq) ^ (br & 7)) * 8)]; \
        } }
    #define RDB(bsel) { \
        _Pragma("unroll") \
        for (int j = 0; j < 4; j++) { \
            int br = wn * 64 + j * 16 + lm; \
            _Pragma("unroll") \
            for (int ks = 0; ks < 2; ks++) \
                bq[j][ks] = *(const bf16x8*)&sm[bsel][1][br >> 6] \
                    [(br & 63) * 64 + (((ks * 4 + lq) ^ (br & 7)) * 8)]; \
        } }
    #define MIDBAR() { \
        __builtin_amdgcn_sched_barrier(0); \
        __builtin_amdgcn_s_barrier(); \
        asm volatile("s_waitcnt lgkmcnt(0)" ::: "memory"); \
        __builtin_amdgcn_sched_barrier(0); }
    #define MMPH(p) { \
        __builtin_amdgcn_s_setprio(1); \
        _Pragma("unroll") \
        for (int ii = 0; ii < 2; ii++) \
            _Pragma("unroll") \
            for (int j = 0; j < 4; j++) { \
                acc[2 * (p) + ii][j] = __builtin_amdgcn_mfma_f32_16x16x32_bf16( \
                    af[ii][0], bq[j][0], acc[2 * (p) + ii][j], 0, 0, 0); \
                acc[2 * (p) + ii][j] = __builtin_amdgcn_mfma_f32_16x16x32_bf16( \
                    af[ii][1], bq[j][1], acc[2 * (p) + ii][j], 0, 0, 0); \
            } \
        __builtin_amdgcn_s_setprio(0); \
        __builtin_amdgcn_sched_barrier(0); }

    f32x4 acc[8][4];
    #pragma unroll
    for (int i = 0; i < 8; i++)
        #pragma unroll
        for (int j = 0; j < 4; j++)
            #pragma unroll
            for (int rr = 0; rr < 4; rr++) acc[i][j][rr] = 0.0f;

    const int NT = Kc >> 6;
    // prologue, exact issue order (oldest->newest) matched to vmcnt(4) math:
    // [0.b0 0.b1][0.a0 0.a2][0.a1 0.a3][0.b2 0.b3][1.b0 1.b1][1.a0 1.a2]
    STB(0, 0, 0); STB(0, 1, 0); STA(0, 0, 0); STA(0, 2, 0);
    STA(0, 1, 0); STA(0, 3, 0); STB(0, 2, 0); STB(0, 3, 0);
    if (NT > 1) { STB(1, 0, 64); STB(1, 1, 64); STA(1, 0, 64); STA(1, 2, 64); }

    bf16x8 bq[4][2], af[2][2];

    for (int t = 0; t < NT; ++t) {
        const int b   = t & 1;
        const int kk1 = (t + 1) * 64;
        const int kk2 = (t + 2) * 64;

        // tile edge: publish tile t's 8 staged units
        if (t == NT - 1) asm volatile("s_waitcnt vmcnt(0)" ::: "memory");
        else             asm volatile("s_waitcnt vmcnt(4)" ::: "memory");
        __builtin_amdgcn_s_barrier();
        __builtin_amdgcn_sched_barrier(0);

        // ---- phase 0
        RDB(b); RDA(b, 0);
        if (t + 1 < NT) { STA(b ^ 1, 1, kk1); STA(b ^ 1, 3, kk1); }
        MIDBAR();
        MMPH(0);

        // ---- phase 1
        RDA(b, 1);
        if (t + 1 < NT) { STB(b ^ 1, 2, kk1); STB(b ^ 1, 3, kk1); }
        MIDBAR();
        MMPH(1);

        // ---- phase 2
        RDA(b, 2);
        if (t + 2 < NT) { STB(b, 0, kk2); STB(b, 1, kk2); }
        MIDBAR();
        MMPH(2);

        // ---- phase 3
        RDA(b, 3);
        if (t + 2 < NT) { STA(b, 0, kk2); STA(b, 2, kk2); }
        MIDBAR();
        MMPH(3);
    }
    #undef STA
    #undef STB
    #undef RDA
    #undef RDB
    #undef MIDBAR
    #undef MMPH

    // epilogue: C/D layout col=lane&15, row=(lane>>4)*4+reg
    const size_t zoff = (size_t)blockIdx.z * (size_t)M * ldc;
    #pragma unroll
    for (int i = 0; i < 8; i++) {
        #pragma unroll
        for (int rr = 0; rr < 4; rr++) {
            int row = row0 + wm * 128 + i * 16 + lq * 4 + rr;
            #pragma unroll
            for (int j = 0; j < 4; j++) {
                int col = col0 + wn * 64 + j * 16 + lm;
                if (col < N) {
                    float v = acc[i][j][rr];
                    if (OBF16 == 1)
                        ((unsigned short*)Cout)[(size_t)row * ldc + col] = f2bf(v);
                    else if (OBF16 == 2)
                        ((unsigned short*)Cout)[zoff + (size_t)row * ldc + col] = f2bf(v);
                    else
                        ((float*)Cout)[zoff + (size_t)row * ldc + col] = v;
                }
            }
        }
    }
}

// Sum nsplit bf16 partial planes; emit fp32 dbc + bf16 copy of cols<64.
__global__ __launch_bounds__(256) void reduce_splitk(
    const unsigned short* __restrict__ part, float* __restrict__ C,
    unsigned short* __restrict__ dtlo16, int n, int nsplit)
{
    int i = blockIdx.x * 256 + threadIdx.x;
    if (i >= n) return;
    float s = 0.0f;
    for (int z = 0; z < nsplit; z++) s += bf2f(part[(size_t)z * n + i]);
    C[i] = s;
    int row = i / 96;
    int col = i - row * 96;
    if (col < DTRANK) dtlo16[row * DTRANK + col] = f2bf(s);
}

// Sum 4 bf16 partial planes (plane stride 4096*1024 ushorts), fp32 out.
// 8 elems/thread via uint4; n8 = total/8.
__global__ __launch_bounds__(256) void reduce4b(
    const unsigned short* __restrict__ part, float* __restrict__ out, int n8)
{
    int i = blockIdx.x * 256 + threadIdx.x;
    if (i >= n8) return;
    const uint4* p4 = (const uint4*)part;
    float a0 = 0, a1 = 0, a2 = 0, a3 = 0, a4 = 0, a5 = 0, a6 = 0, a7 = 0;
    #pragma unroll
    for (int z = 0; z < 4; z++) {
        uint4 v = p4[(size_t)z * 524288 + i];   // 4194304 ushorts / 8 per uint4
        a0 += bf2f((unsigned short)(v.x & 0xffff)); a1 += bf2f((unsigned short)(v.x >> 16));
        a2 += bf2f((unsigned short)(v.y & 0xffff)); a3 += bf2f((unsigned short)(v.y >> 16));
        a4 += bf2f((unsigned short)(v.z & 0xffff)); a5 += bf2f((unsigned short)(v.z >> 16));
        a6 += bf2f((unsigned short)(v.w & 0xffff)); a7 += bf2f((unsigned short)(v.w >> 16));
    }
    float4 o0 = {a0, a1, a2, a3};
    float4 o1 = {a4, a5, a6, a7};
    *(float4*)(out + (size_t)i * 8)     = o0;
    *(float4*)(out + (size_t)i * 8 + 4) = o1;
}

// conv + silu, register-rolling window along l. Reads bf16 xz (cols 0..2048),
// emits bf16 xc16. grid (8, 64, 2).
__global__ __launch_bounds__(256) void conv_silu_v2(
    const unsigned short* __restrict__ xz16, const float* __restrict__ conv_w,
    const float* __restrict__ conv_b, unsigned short* __restrict__ xc16)
{
    const int tid = threadIdx.x;
    const int d   = blockIdx.x * 256 + tid;
    const int l0  = blockIdx.y * 32;
    const int b   = blockIdx.z;
    const float4 w  = *(const float4*)(conv_w + d * 4);
    const float bias = conv_b[d];
    const int t0 = b * L_SZ + l0;
    const unsigned short* src = xz16 + (size_t)t0 * 4096 + d;

    float r0, r1, r2;
    if (l0 == 0) {
        r0 = r1 = r2 = 0.0f;
    } else {
        r0 = bf2f(src[-3 * 4096]);
        r1 = bf2f(src[-2 * 4096]);
        r2 = bf2f(src[-1 * 4096]);
    }
    #pragma unroll 4
    for (int l = 0; l < 32; l++) {
        float r3 = bf2f(src[(size_t)l * 4096]);
        float acc = bias + r0 * w.x + r1 * w.y + r2 * w.z + r3 * w.w;
        xc16[(size_t)(t0 + l) * DINNER + d] = f2bf(silu_f(acc));
        r0 = r1; r1 = r2; r2 = r3;
    }
}

// ---- Chunked parallel selective scan (CS=32, 1024 blocks) -------------------
// v6: pass1 emits per-chunk delta-sum sd (1MB) instead of P=exp(A*sd) (16MB);
// pass2 recomputes p on the fly. bf16 delta input, packed f32x2 math.
// grid: B * NCH * 8 = 1024; db=blk&7, c=(blk>>3)&63, b=blk>>9.
__global__ __launch_bounds__(256) void scan_pass1(
    const unsigned short* __restrict__ xc16, const unsigned short* __restrict__ delta16,
    const float* __restrict__ dbc, const float* __restrict__ A_log,
    float* __restrict__ sdv, float* __restrict__ E)
{
    __shared__ float Bs[CS * DSTATE];
    const int tid = threadIdx.x;
    const int db  = blockIdx.x & 7;
    const int c   = (blockIdx.x >> 3) & (NCH - 1);
    const int b   = blockIdx.x >> 9;
    const int d   = db * 256 + tid;
    const int t0  = b * L_SZ + c * CS;

    for (int idx = tid; idx < CS * DSTATE; idx += 256) {
        int step = idx >> 4, i = idx & 15;
        Bs[idx] = dbc[(t0 + step) * 96 + DTRANK + i];
    }

    f32x2 A2v[8], Er2[8];
    const float* Ap = A_log + d * DSTATE;
    #pragma unroll
    for (int p = 0; p < 8; p++) {
        A2v[p].x = -1.44269504f * __expf(Ap[2 * p]);
        A2v[p].y = -1.44269504f * __expf(Ap[2 * p + 1]);
        Er2[p].x = 0.0f; Er2[p].y = 0.0f;
    }
    float sd = 0.0f;

    const unsigned short* dp = delta16 + (size_t)t0 * DINNER + d;
    const unsigned short* up = xc16 + (size_t)t0 * DINNER + d;

    float dv[4], uv[4];
    #pragma unroll
    for (int q = 0; q < 4; q++) {
        dv[q] = bf2f(dp[(size_t)q * DINNER]);
        uv[q] = bf2f(up[(size_t)q * DINNER]);
    }
    __syncthreads();

    for (int lo = 0; lo < CS; lo += 4) {
        float nd[4], nu[4];
        if (lo + 4 < CS) {
            #pragma unroll
            for (int q = 0; q < 4; q++) {
                nd[q] = bf2f(dp[(size_t)(lo + 4 + q) * DINNER]);
                nu[q] = bf2f(up[(size_t)(lo + 4 + q) * DINNER]);
            }
        }
        #pragma unroll
        for (int q = 0; q < 4; q++) {
            const float dvq = dv[q];
            const float du  = dvq * uv[q];
            sd += dvq;
            const f32x4* Bv = (const f32x4*)&Bs[(lo + q) * DSTATE];
            f32x4 b0 = Bv[0], b1 = Bv[1], b2 = Bv[2], b3 = Bv[3];
            #define P1PAIR(p, bb) { \
                f32x2 m = dvq * A2v[p]; \
                f32x2 e; e.x = fexp2(m.x); e.y = fexp2(m.y); \
                Er2[p] = e * Er2[p] + du * (bb); }
            P1PAIR(0, b0.xy) P1PAIR(1, b0.zw)
            P1PAIR(2, b1.xy) P1PAIR(3, b1.zw)
            P1PAIR(4, b2.xy) P1PAIR(5, b2.zw)
            P1PAIR(6, b3.xy) P1PAIR(7, b3.zw)
            #undef P1PAIR
        }
        #pragma unroll
        for (int q = 0; q < 4; q++) { dv[q] = nd[q]; uv[q] = nu[q]; }
    }

    sdv[(size_t)(b * NCH + c) * DINNER + d] = sd;
    const long long o = ((long long)((b * NCH + c) * DINNER) + d) * DSTATE;
    #pragma unroll
    for (int w = 0; w < 4; w++) {
        f32x4 ev;
        #pragma unroll
        for (int k = 0; k < 2; k++) {
            int p = w * 2 + k;
            ev[2 * k]     = Er2[p].x;
            ev[2 * k + 1] = Er2[p].y;
        }
        *(f32x4*)(E + o + w * 4) = ev;
    }
}

// pass2: sequential inter-chunk prefix. p recomputed from sd + A_log.
// rest = d*16+s, so A_log[rest] is the coalesced per-thread decay param.
__global__ __launch_bounds__(256) void scan_pass2(
    const float* __restrict__ sdv, const float* __restrict__ A_log,
    float* __restrict__ E)
{
    const int gid  = blockIdx.x * 256 + threadIdx.x;
    const int b    = gid >> 15;
    const int rest = gid & 32767;
    const int d    = rest >> 4;
    const float A2 = -1.44269504f * __expf(A_log[rest]);
    float h = 0.0f;
    for (int c = 0; c < NCH; c++) {
        const long long idx = (long long)(b * NCH + c) * (DINNER * DSTATE) + rest;
        float p = fexp2(A2 * sdv[(size_t)(b * NCH + c) * DINNER + d]);
        float e = E[idx];
        E[idx] = h;
        h = p * h + e;
    }
}

// pass3: bf16 delta, packed math, fused silu(z) gate, bf16 y out.
__global__ __launch_bounds__(256) void scan_pass3(
    const unsigned short* __restrict__ xc16, const unsigned short* __restrict__ delta16,
    const float* __restrict__ dbc, const float* __restrict__ A_log,
    const float* __restrict__ D_skip, const float* __restrict__ Hin,
    const unsigned short* __restrict__ xz16, unsigned short* __restrict__ y16)
{
    __shared__ float BCs[CS * 2 * DSTATE];
    const int tid = threadIdx.x;
    const int db  = blockIdx.x & 7;
    const int c   = (blockIdx.x >> 3) & (NCH - 1);
    const int b   = blockIdx.x >> 9;
    const int d   = db * 256 + tid;
    const int t0  = b * L_SZ + c * CS;

    for (int idx = tid; idx < CS * 2 * DSTATE; idx += 256) {
        int step = idx >> 5, i = idx & 31;
        BCs[idx] = dbc[(t0 + step) * 96 + DTRANK + i];
    }

    f32x2 A2v[8], h2[8];
    const float* Ap = A_log + d * DSTATE;
    const long long o = ((long long)((b * NCH + c) * DINNER) + d) * DSTATE;
    #pragma unroll
    for (int p = 0; p < 8; p++) {
        A2v[p].x = -1.44269504f * __expf(Ap[2 * p]);
        A2v[p].y = -1.44269504f * __expf(Ap[2 * p + 1]);
        h2[p].x = Hin[o + 2 * p];
        h2[p].y = Hin[o + 2 * p + 1];
    }
    const float Dv = D_skip[d];

    const unsigned short* dp = delta16 + (size_t)t0 * DINNER + d;
    const unsigned short* up = xc16 + (size_t)t0 * DINNER + d;
    const unsigned short* zp = xz16 + (size_t)t0 * 4096 + DINNER + d;
    unsigned short* yp = y16 + (size_t)t0 * DINNER + d;

    float dv[4], uv[4], zv[4];
    #pragma unroll
    for (int q = 0; q < 4; q++) {
        dv[q] = bf2f(dp[(size_t)q * DINNER]);
        uv[q] = bf2f(up[(size_t)q * DINNER]);
        zv[q] = bf2f(zp[(size_t)q * 4096]);
    }
    __syncthreads();

    for (int lo = 0; lo < CS; lo += 4) {
        float nd[4], nu[4], nz[4];
        if (lo + 4 < CS) {
            #pragma unroll
            for (int q = 0; q < 4; q++) {
                nd[q] = bf2f(dp[(size_t)(lo + 4 + q) * DINNER]);
                nu[q] = bf2f(up[(size_t)(lo + 4 + q) * DINNER]);
                nz[q] = bf2f(zp[(size_t)(lo + 4 + q) * 4096]);
            }
        }
        #pragma unroll
        for (int q = 0; q < 4; q++) {
            const float dvq = dv[q];
            const float uvq = uv[q];
            const float du  = dvq * uvq;
            const f32x4* Bv = (const f32x4*)&BCs[(lo + q) * 32];
            f32x4 b0 = Bv[0], b1 = Bv[1], b2 = Bv[2], b3 = Bv[3];
            f32x4 c0 = Bv[4], c1 = Bv[5], c2 = Bv[6], c3 = Bv[7];
            f32x2 y0; y0.x = 0.0f; y0.y = 0.0f;
            f32x2 y1; y1.x = 0.0f; y1.y = 0.0f;
            #define P3PAIR(p, bb, cc, ya) { \
                f32x2 m = dvq * A2v[p]; \
                f32x2 e; e.x = fexp2(m.x); e.y = fexp2(m.y); \
                h2[p] = e * h2[p] + du * (bb); \
                ya = ya + h2[p] * (cc); }
            P3PAIR(0, b0.xy, c0.xy, y0) P3PAIR(1, b0.zw, c0.zw, y1)
            P3PAIR(2, b1.xy, c1.xy, y0) P3PAIR(3, b1.zw, c1.zw, y1)
            P3PAIR(4, b2.xy, c2.xy, y0) P3PAIR(5, b2.zw, c2.zw, y1)
            P3PAIR(6, b3.xy, c3.xy, y0) P3PAIR(7, b3.zw, c3.zw, y1)
            #undef P3PAIR
            f32x2 ys = y0 + y1;
            float yv = ys.x + ys.y;
            yp[(size_t)(lo + q) * DINNER] = f2bf((uvq * Dv + yv) * silu_f(zv[q]));
        }
        #pragma unroll
        for (int q = 0; q < 4; q++) { dv[q] = nd[q]; uv[q] = nu[q]; zv[q] = nz[q]; }
    }
}

extern "C" void kernel_launch(void* const* d_in, const int* in_sizes, int n_in,
                              void* d_out, int out_size, void* d_ws, size_t ws_size,
                              hipStream_t stream) {
    const float* x       = (const float*)d_in[0];
    const float* W_in    = (const float*)d_in[1];
    const float* conv_w  = (const float*)d_in[2];
    const float* conv_b  = (const float*)d_in[3];
    const float* W_xproj = (const float*)d_in[4];
    const float* W_dt    = (const float*)d_in[5];
    const float* b_dt    = (const float*)d_in[6];
    const float* A_log   = (const float*)d_in[7];
    const float* D_skip  = (const float*)d_in[8];
    const float* W_out   = (const float*)d_in[9];
    float* out = (float*)d_out;

    // workspace layout, float units. Aliases (dead-before-reuse):
    //   x16 (dead after gemm1)      shares yb16 (written at pass3)
    //   parts6u (GEMM6 bf16 partials, 16.7M ushorts = 8.4M f) spans
    //     [13107200, 21495808) = delta16 + freed gap — delta16 dead after
    //     pass3; disjoint from Ebuf which pass3 reads. GEMM6 runs after.
    //   parts3u (GEMM3 bf16 partials, 3.1M ushorts = 1.57M f) + sdbuf
    //     (262144 f) live in the old Pbuf span [25690112, 29884416).
    float* ws = (float*)d_ws;
    unsigned short* xz16   = (unsigned short*)ws;              // [0 .. 8388608) f
    unsigned short* xc16   = (unsigned short*)(ws +  8388608); // [.. 12582912) f
    float* dbc             = ws + 12582912;                    // [.. 12976128) f
    unsigned short* dtlo16 = (unsigned short*)(ws + 12976128); // [.. 13107200) f
    unsigned short* delta16 = (unsigned short*)(ws + 13107200); // [.. 17301504) f
    unsigned short* parts6u = (unsigned short*)(ws + 13107200); //  alias, [.. 21495808) f
    float* Ebuf            = ws + 21495808;                    // [.. 25690112) f : 2*64*2048*16
    unsigned short* parts3u = (unsigned short*)(ws + 25690112); // [.. 27262976) f
    float* sdbuf           = ws + 27262976;                    // [.. 27525120) f : 2*64*2048
    unsigned short* yb16   = (unsigned short*)(ws + 29884416); // [.. 31981568) f
    unsigned short* x16    = yb16;                             //   alias
    unsigned short* W_inT    = (unsigned short*)(ws + 31981568); // [.. 34078720) f
    unsigned short* W_xprojT = (unsigned short*)(ws + 34078720); // [.. 34177024) f
    unsigned short* W_dtT    = (unsigned short*)(ws + 34177024); // [.. 34242560) f
    unsigned short* W_outT   = (unsigned short*)(ws + 34242560); // [.. 35291136) f

    const int MT = 4096;  // B*L tokens

    // 0) all weight transposes + x cast in ONE kernel (8512 blocks)
    prep_all<<<dim3(8512), 256, 0, stream>>>(
        W_in, W_inT, W_xproj, W_xprojT, W_dt, W_dtT, W_out, W_outT, x, x16);

    // 1) xz = x @ W_in              (4096 x 4096, K=1024) -> bf16, 8-phase v3
    gemm_8ph<1><<<dim3(256), 512, 0, stream>>>(
        x16, W_inT, xz16, MT, 4096, 1024, 1024, 4096, 1024);

    // 2) xc16 = silu(causal_dwconv(xin) + b)
    conv_silu_v2<<<dim3(8, 64, 2), 256, 0, stream>>>(xz16, conv_w, conv_b, xc16);

    // 3) dbc = xc @ W_xproj         (4096 x 96, K=2048) — split-K x8, bf16 parts
    gemm_bt_lds<0, 1><<<dim3(1, 32, 8), 256, 0, stream>>>(
        xc16, W_xprojT, parts3u, nullptr, MT, 96, 2048, 2048, 2048, 96, 256);
    reduce_splitk<<<dim3(1536), 256, 0, stream>>>(parts3u, dbc, dtlo16, MT * 96, 8);

    // 4) delta16 = softplus(dt_lo @ W_dt + b_dt)  (4096 x 2048, K=64) -> bf16
    gemm_bt_lds<1, 1><<<dim3(16, 32), 256, 0, stream>>>(
        dtlo16, W_dtT, delta16, b_dt, MT, 2048, 64, 64, 64, 2048, 64);

    // 5) chunked selective scan + fused gate (bf16 y out); sd instead of P
    scan_pass1<<<dim3(1024), 256, 0, stream>>>(xc16, delta16, dbc, A_log, sdbuf, Ebuf);
    scan_pass2<<<dim3(256), 256, 0, stream>>>(sdbuf, A_log, Ebuf);
    scan_pass3<<<dim3(1024), 256, 0, stream>>>(xc16, delta16, dbc, A_log, D_skip,
                                               Ebuf, xz16, yb16);

    // 6) out = y @ W_out   (4096 x 1024, K=2048) — 8-phase v3, split-K x4,
    //    bf16 partials (OBF16=2), ldb = 2048 (W_outT row stride = K).
    gemm_8ph<2><<<dim3(64, 1, 4), 512, 0, stream>>>(
        yb16, W_outT, parts6u, MT, 1024, 2048, 2048, 1024, 512);
    reduce4b<<<dim3(2048), 256, 0, stream>>>(parts6u, out, MT * 1024 / 8);
}

// Round 10
// 278.651 us; speedup vs baseline: 1.0930x; 1.0273x over previous
//
#include <hip/hip_runtime.h>
#include <math.h>

#define B_SZ 2
#define L_SZ 2048
#define DMODEL 1024
#define DINNER 2048
#define DSTATE 16
#define DCONV 4
#define DTRANK 64

#define CS 32                    // scan chunk size
#define NCH (L_SZ / CS)          // 64 chunks per batch

typedef float f32x4 __attribute__((ext_vector_type(4)));
typedef float f32x2 __attribute__((ext_vector_type(2)));
typedef __bf16 bf16x8 __attribute__((ext_vector_type(8)));

__device__ __forceinline__ float silu_f(float x) {
    return x / (1.0f + __expf(-x));
}

// fast softplus: max(x,0) + log(1+exp(-|x|)); abs err ~1e-6, branch-free tails
__device__ __forceinline__ float softplus_f(float x) {
    return fmaxf(x, 0.0f) + __logf(1.0f + __expf(-fabsf(x)));
}

// raw v_exp_f32: computes 2^x (hardware trans op, no pre-multiply)
__device__ __forceinline__ float fexp2(float x) {
    float r;
    asm("v_exp_f32 %0, %1" : "=v"(r) : "v"(x));
    return r;
}

// fp32 -> bf16 round-to-nearest-even on raw bits
__device__ __forceinline__ unsigned short f2bf(float x) {
    unsigned int u = __float_as_uint(x);
    u = u + 0x7FFFu + ((u >> 16) & 1u);
    return (unsigned short)(u >> 16);
}

__device__ __forceinline__ float bf2f(unsigned short s) {
    return __uint_as_float(((unsigned int)s) << 16);
}

// async global->LDS DMA, 16B per lane; deposits at base + lane*16B.
__device__ __forceinline__ void gload_lds16(const unsigned short* g, unsigned short* l) {
    __builtin_amdgcn_global_load_lds(
        (const __attribute__((address_space(1))) void*)g,
        (__attribute__((address_space(3))) void*)l, 16, 0, 0);
}

union Pack8 { unsigned short s[8]; uint4 v; };

// transpose+cast tile body: W[R,C] fp32 -> WT[C,R] bf16, 32x32 tile (bx,by)
__device__ __forceinline__ void tc_tile(
    const float* __restrict__ W, unsigned short* __restrict__ WT,
    int R, int C, int bx, int by, float (*t)[33])
{
    const int tx = threadIdx.x & 31;
    const int ty = threadIdx.x >> 5;
    const int r0 = by * 32;
    const int c0 = bx * 32;
    #pragma unroll
    for (int i = 0; i < 4; i++)
        t[ty + i * 8][tx] = W[(size_t)(r0 + ty + i * 8) * C + c0 + tx];
    __syncthreads();
    #pragma unroll
    for (int i = 0; i < 4; i++)
        WT[(size_t)(c0 + ty + i * 8) * R + r0 + tx] = f2bf(t[tx][ty + i * 8]);
}

// ONE prep kernel: all 4 weight transposes + x cast. 1D grid, range dispatch.
// blocks: [0,4096) W_in | [4096,4288) W_xproj | [4288,4416) W_dt |
//         [4416,6464) W_out | [6464,8512) cast x (2048 blocks)
__global__ __launch_bounds__(256) void prep_all(
    const float* __restrict__ W_in,    unsigned short* __restrict__ W_inT,
    const float* __restrict__ W_xproj, unsigned short* __restrict__ W_xprojT,
    const float* __restrict__ W_dt,    unsigned short* __restrict__ W_dtT,
    const float* __restrict__ W_out,   unsigned short* __restrict__ W_outT,
    const float* __restrict__ x,       unsigned short* __restrict__ x16)
{
    __shared__ float t[32][33];
    int b = blockIdx.x;
    if (b < 4096) { tc_tile(W_in, W_inT, 1024, 4096, b % 128, b / 128, t); return; }
    b -= 4096;
    if (b < 192)  { tc_tile(W_xproj, W_xprojT, 2048, 96, b % 3, b / 3, t); return; }
    b -= 192;
    if (b < 128)  { tc_tile(W_dt, W_dtT, 64, 2048, b % 64, b / 64, t); return; }
    b -= 128;
    if (b < 2048) { tc_tile(W_out, W_outT, 2048, 1024, b % 32, b / 32, t); return; }
    b -= 2048;
    // cast x -> bf16, 8 elems/thread (2048 blocks x 256 thr x 8 = 4194304)
    int i = b * 256 + threadIdx.x;
    const float4 f0 = *(const float4*)(x + (size_t)i * 8);
    const float4 f1 = *(const float4*)(x + (size_t)i * 8 + 4);
    Pack8 p;
    p.s[0] = f2bf(f0.x); p.s[1] = f2bf(f0.y); p.s[2] = f2bf(f0.z); p.s[3] = f2bf(f0.w);
    p.s[4] = f2bf(f1.x); p.s[5] = f2bf(f1.y); p.s[6] = f2bf(f1.z); p.s[7] = f2bf(f1.w);
    *(uint4*)(x16 + (size_t)i * 8) = p.v;
}

// ---- bf16 MFMA GEMM, B pre-transposed, global_load_lds staging -------------
// (128x128 2-phase kernel, kept for the small GEMMs 3 and 4.)
// OBF16=1 writes bf16 (with z-plane offset), 0 writes fp32 (with z-plane).
template <int ACT, int OBF16>
__global__ __launch_bounds__(256) void gemm_bt_lds(
    const unsigned short* __restrict__ A, const unsigned short* __restrict__ BT,
    void* __restrict__ Cout, const float* __restrict__ bias,
    int M, int N, int K, int lda, int ldb, int ldc, int Kc)
{
    __shared__ unsigned short As[128 * 64];
    __shared__ unsigned short Bs[128 * 64];

    const int tid  = threadIdx.x;
    const int lane = tid & 63;
    const int wave = tid >> 6;
    const int wm   = wave >> 1;
    const int wn   = wave & 1;
    const int row0 = blockIdx.y * 128;
    const int col0 = blockIdx.x * 128;
    const int lq   = lane >> 4;
    const int lm   = lane & 15;
    const int kbeg = blockIdx.z * Kc;

    const int rloc = wave * 32 + (lane >> 3);
    const int sc   = (lane & 7) ^ ((lane >> 3) & 7);
    const unsigned short* gA = A + (size_t)(row0 + rloc) * lda + sc * 8;
    const unsigned short* gBp[4];
    #pragma unroll
    for (int is = 0; is < 4; is++) {
        int br = col0 + rloc + 8 * is;
        if (br > N - 1) br = N - 1;
        gBp[is] = BT + (size_t)br * ldb + sc * 8;
    }
    unsigned short* lA = As + wave * 2048;
    unsigned short* lB = Bs + wave * 2048;

    f32x4 acc[4][4];
    #pragma unroll
    for (int i = 0; i < 4; i++)
        #pragma unroll
        for (int j = 0; j < 4; j++)
            #pragma unroll
            for (int r = 0; r < 4; r++) acc[i][j][r] = 0.0f;

    for (int k0 = kbeg; k0 < kbeg + Kc; k0 += 64) {
        #pragma unroll
        for (int is = 0; is < 4; is++) {
            gload_lds16(gA + (size_t)(8 * is) * lda + k0, lA + is * 512);
            gload_lds16(gBp[is] + k0, lB + is * 512);
        }
        __syncthreads();

        #pragma unroll
        for (int ks = 0; ks < 2; ks++) {
            bf16x8 af[4], bfr[4];
            #pragma unroll
            for (int i = 0; i < 4; i++) {
                int row = wm * 64 + i * 16 + lm;
                af[i] = *(const bf16x8*)&As[row * 64 + (((ks * 4 + lq) ^ (row & 7)) * 8)];
            }
            #pragma unroll
            for (int j = 0; j < 4; j++) {
                int row = wn * 64 + j * 16 + lm;
                bfr[j] = *(const bf16x8*)&Bs[row * 64 + (((ks * 4 + lq) ^ (row & 7)) * 8)];
            }
            #pragma unroll
            for (int i = 0; i < 4; i++)
                #pragma unroll
                for (int j = 0; j < 4; j++)
                    acc[i][j] = __builtin_amdgcn_mfma_f32_16x16x32_bf16(
                        af[i], bfr[j], acc[i][j], 0, 0, 0);
        }
        __syncthreads();
    }

    // epilogue: C/D layout col=lane&15, row=(lane>>4)*4+reg
    #pragma unroll
    for (int i = 0; i < 4; i++) {
        #pragma unroll
        for (int r = 0; r < 4; r++) {
            int row = row0 + wm * 64 + i * 16 + lq * 4 + r;
            #pragma unroll
            for (int j = 0; j < 4; j++) {
                int col = col0 + wn * 64 + j * 16 + lm;
                if (col < N) {
                    float v = acc[i][j][r];
                    if (ACT == 1) v = softplus_f(v + bias[col]);
                    if (OBF16) {
                        unsigned short* Cz = (unsigned short*)Cout +
                            (size_t)blockIdx.z * (size_t)M * ldc;
                        Cz[(size_t)row * ldc + col] = f2bf(v);
                    } else {
                        float* Cz = (float*)Cout +
                            (size_t)blockIdx.z * (size_t)M * ldc;
                        Cz[(size_t)row * ldc + col] = v;
                    }
                }
            }
        }
    }
}

// ---- 256x256 8-phase bf16 GEMM, m201-faithful mid-phase barrier (v3) -------
// OBF16: 0 = fp32 out (with z-offset), 1 = bf16 out (no z-offset),
//        2 = bf16 out with z-offset (split-K bf16 partials).
template <int OBF16>
__global__ __launch_bounds__(512, 2) void gemm_8ph(
    const unsigned short* __restrict__ A, const unsigned short* __restrict__ BT,
    void* __restrict__ Cout, int M, int N, int lda, int ldb, int ldc, int Kc)
{
    __shared__ unsigned short sm[2][2][4][64 * 64];

    const int tid  = threadIdx.x;
    const int lane = tid & 63;
    const int wave = tid >> 6;         // 0..7
    const int wm   = wave >> 2;        // 0..1  (128-row half)
    const int wn   = wave & 3;         // 0..3  (64-col quarter)
    const int lq   = lane >> 4;
    const int lm   = lane & 15;

    // bijective XCD swizzle (gridDim.x % 8 == 0 guaranteed by caller)
    const int cpx = gridDim.x >> 3;
    const int ti  = (blockIdx.x & 7) * cpx + (blockIdx.x >> 3);
    const int nbx = N >> 8;
    const int row0 = (ti / nbx) * 256;
    const int col0 = (ti % nbx) * 256;
    const int kbeg = blockIdx.z * Kc;

    // staging: one gload per thread per 64-row unit (512 thr x 16B = 8KB)
    const int r  = tid >> 3;                 // row within unit, 0..63
    const int sc = (tid & 7) ^ (r & 7);      // pre-swizzled source group
    const unsigned short* gA = A + (size_t)(row0 + r) * lda + sc * 8 + kbeg;
    const unsigned short* gB[4];
    #pragma unroll
    for (int u = 0; u < 4; u++) {
        int br = col0 + u * 64 + r;
        if (br > N - 1) br = N - 1;
        gB[u] = BT + (size_t)br * ldb + sc * 8 + kbeg;
    }

    #define STA(bsel, u, kk) gload_lds16(gA + (size_t)((u) * 64) * lda + (kk), \
                                         &sm[bsel][0][u][wave * 512])
    #define STB(bsel, u, kk) gload_lds16(gB[u] + (kk), &sm[bsel][1][u][wave * 512])

    // LDS-read macros. RDA: A i-pair (2*pr, 2*pr+1) from buffer bsel.
    #define RDA(bsel, pr) { \
        _Pragma("unroll") \
        for (int ii = 0; ii < 2; ii++) { \
            int br = wm * 128 + ((pr) * 2 + ii) * 16 + lm; \
            _Pragma("unroll") \
            for (int ks = 0; ks < 2; ks++) \
                af[ii][ks] = *(const bf16x8*)&sm[bsel][0][br >> 6] \
                    [(br & 63) * 64 + (((ks * 4 + lq) ^ (br & 7)) * 8)]; \
        } }
    #define RDB(bsel) { \
        _Pragma("unroll") \
        for (int j = 0; j < 4; j++) { \
            int br = wn * 64 + j * 16 + lm; \
            _Pragma("unroll") \
            for (int ks = 0; ks < 2; ks++) \
                bq[j][ks] = *(const bf16x8*)&sm[bsel][1][br >> 6] \
                    [(br & 63) * 64 + (((ks * 4 + lq) ^ (br & 7)) * 8)]; \
        } }
    #define MIDBAR() { \
        __builtin_amdgcn_sched_barrier(0); \
        __builtin_amdgcn_s_barrier(); \
        asm volatile("s_waitcnt lgkmcnt(0)" ::: "memory"); \
        __builtin_amdgcn_sched_barrier(0); }
    #define MMPH(p) { \
        __builtin_amdgcn_s_setprio(1); \
        _Pragma("unroll") \
        for (int ii = 0; ii < 2; ii++) \
            _Pragma("unroll") \
            for (int j = 0; j < 4; j++) { \
                acc[2 * (p) + ii][j] = __builtin_amdgcn_mfma_f32_16x16x32_bf16( \
                    af[ii][0], bq[j][0], acc[2 * (p) + ii][j], 0, 0, 0); \
                acc[2 * (p) + ii][j] = __builtin_amdgcn_mfma_f32_16x16x32_bf16( \
                    af[ii][1], bq[j][1], acc[2 * (p) + ii][j], 0, 0, 0); \
            } \
        __builtin_amdgcn_s_setprio(0); \
        __builtin_amdgcn_sched_barrier(0); }

    f32x4 acc[8][4];
    #pragma unroll
    for (int i = 0; i < 8; i++)
        #pragma unroll
        for (int j = 0; j < 4; j++)
            #pragma unroll
            for (int rr = 0; rr < 4; rr++) acc[i][j][rr] = 0.0f;

    const int NT = Kc >> 6;
    // prologue, exact issue order (oldest->newest) matched to vmcnt(4) math:
    // [0.b0 0.b1][0.a0 0.a2][0.a1 0.a3][0.b2 0.b3][1.b0 1.b1][1.a0 1.a2]
    STB(0, 0, 0); STB(0, 1, 0); STA(0, 0, 0); STA(0, 2, 0);
    STA(0, 1, 0); STA(0, 3, 0); STB(0, 2, 0); STB(0, 3, 0);
    if (NT > 1) { STB(1, 0, 64); STB(1, 1, 64); STA(1, 0, 64); STA(1, 2, 64); }

    bf16x8 bq[4][2], af[2][2];

    for (int t = 0; t < NT; ++t) {
        const int b   = t & 1;
        const int kk1 = (t + 1) * 64;
        const int kk2 = (t + 2) * 64;

        // tile edge: publish tile t's 8 staged units
        if (t == NT - 1) asm volatile("s_waitcnt vmcnt(0)" ::: "memory");
        else             asm volatile("s_waitcnt vmcnt(4)" ::: "memory");
        __builtin_amdgcn_s_barrier();
        __builtin_amdgcn_sched_barrier(0);

        // ---- phase 0
        RDB(b); RDA(b, 0);
        if (t + 1 < NT) { STA(b ^ 1, 1, kk1); STA(b ^ 1, 3, kk1); }
        MIDBAR();
        MMPH(0);

        // ---- phase 1
        RDA(b, 1);
        if (t + 1 < NT) { STB(b ^ 1, 2, kk1); STB(b ^ 1, 3, kk1); }
        MIDBAR();
        MMPH(1);

        // ---- phase 2
        RDA(b, 2);
        if (t + 2 < NT) { STB(b, 0, kk2); STB(b, 1, kk2); }
        MIDBAR();
        MMPH(2);

        // ---- phase 3
        RDA(b, 3);
        if (t + 2 < NT) { STA(b, 0, kk2); STA(b, 2, kk2); }
        MIDBAR();
        MMPH(3);
    }
    #undef STA
    #undef STB
    #undef RDA
    #undef RDB
    #undef MIDBAR
    #undef MMPH

    // epilogue: C/D layout col=lane&15, row=(lane>>4)*4+reg
    const size_t zoff = (size_t)blockIdx.z * (size_t)M * ldc;
    #pragma unroll
    for (int i = 0; i < 8; i++) {
        #pragma unroll
        for (int rr = 0; rr < 4; rr++) {
            int row = row0 + wm * 128 + i * 16 + lq * 4 + rr;
            #pragma unroll
            for (int j = 0; j < 4; j++) {
                int col = col0 + wn * 64 + j * 16 + lm;
                if (col < N) {
                    float v = acc[i][j][rr];
                    if (OBF16 == 1)
                        ((unsigned short*)Cout)[(size_t)row * ldc + col] = f2bf(v);
                    else if (OBF16 == 2)
                        ((unsigned short*)Cout)[zoff + (size_t)row * ldc + col] = f2bf(v);
                    else
                        ((float*)Cout)[zoff + (size_t)row * ldc + col] = v;
                }
            }
        }
    }
}

// Sum nsplit bf16 partial planes; emit fp32 dbc + bf16 copy of cols<64.
__global__ __launch_bounds__(256) void reduce_splitk(
    const unsigned short* __restrict__ part, float* __restrict__ C,
    unsigned short* __restrict__ dtlo16, int n, int nsplit)
{
    int i = blockIdx.x * 256 + threadIdx.x;
    if (i >= n) return;
    float s = 0.0f;
    for (int z = 0; z < nsplit; z++) s += bf2f(part[(size_t)z * n + i]);
    C[i] = s;
    int row = i / 96;
    int col = i - row * 96;
    if (col < DTRANK) dtlo16[row * DTRANK + col] = f2bf(s);
}

// Sum 4 bf16 partial planes (plane stride 4096*1024 ushorts), fp32 out.
// 8 elems/thread via uint4; n8 = total/8.
__global__ __launch_bounds__(256) void reduce4b(
    const unsigned short* __restrict__ part, float* __restrict__ out, int n8)
{
    int i = blockIdx.x * 256 + threadIdx.x;
    if (i >= n8) return;
    const uint4* p4 = (const uint4*)part;
    float a0 = 0, a1 = 0, a2 = 0, a3 = 0, a4 = 0, a5 = 0, a6 = 0, a7 = 0;
    #pragma unroll
    for (int z = 0; z < 4; z++) {
        uint4 v = p4[(size_t)z * 524288 + i];   // 4194304 ushorts / 8 per uint4
        a0 += bf2f((unsigned short)(v.x & 0xffff)); a1 += bf2f((unsigned short)(v.x >> 16));
        a2 += bf2f((unsigned short)(v.y & 0xffff)); a3 += bf2f((unsigned short)(v.y >> 16));
        a4 += bf2f((unsigned short)(v.z & 0xffff)); a5 += bf2f((unsigned short)(v.z >> 16));
        a6 += bf2f((unsigned short)(v.w & 0xffff)); a7 += bf2f((unsigned short)(v.w >> 16));
    }
    float4 o0 = {a0, a1, a2, a3};
    float4 o1 = {a4, a5, a6, a7};
    *(float4*)(out + (size_t)i * 8)     = o0;
    *(float4*)(out + (size_t)i * 8 + 4) = o1;
}

// conv + silu, register-rolling window along l. Reads bf16 xz (cols 0..2048),
// emits bf16 xc16. grid (8, 64, 2).
__global__ __launch_bounds__(256) void conv_silu_v2(
    const unsigned short* __restrict__ xz16, const float* __restrict__ conv_w,
    const float* __restrict__ conv_b, unsigned short* __restrict__ xc16)
{
    const int tid = threadIdx.x;
    const int d   = blockIdx.x * 256 + tid;
    const int l0  = blockIdx.y * 32;
    const int b   = blockIdx.z;
    const float4 w  = *(const float4*)(conv_w + d * 4);
    const float bias = conv_b[d];
    const int t0 = b * L_SZ + l0;
    const unsigned short* src = xz16 + (size_t)t0 * 4096 + d;

    float r0, r1, r2;
    if (l0 == 0) {
        r0 = r1 = r2 = 0.0f;
    } else {
        r0 = bf2f(src[-3 * 4096]);
        r1 = bf2f(src[-2 * 4096]);
        r2 = bf2f(src[-1 * 4096]);
    }
    #pragma unroll 4
    for (int l = 0; l < 32; l++) {
        float r3 = bf2f(src[(size_t)l * 4096]);
        float acc = bias + r0 * w.x + r1 * w.y + r2 * w.z + r3 * w.w;
        xc16[(size_t)(t0 + l) * DINNER + d] = f2bf(silu_f(acc));
        r0 = r1; r1 = r2; r2 = r3;
    }
}

// ---- Chunked parallel selective scan (CS=32, 1024 blocks) -------------------
// v7: E buffer in bf16 (halves the 268MB E traffic); pass1 emits per-chunk
// delta-sum sd; pass2 recomputes p on the fly, fp32 running h, bf16 stores.
// grid: B * NCH * 8 = 1024; db=blk&7, c=(blk>>3)&63, b=blk>>9.
__global__ __launch_bounds__(256) void scan_pass1(
    const unsigned short* __restrict__ xc16, const unsigned short* __restrict__ delta16,
    const float* __restrict__ dbc, const float* __restrict__ A_log,
    float* __restrict__ sdv, unsigned short* __restrict__ E)
{
    __shared__ float Bs[CS * DSTATE];
    const int tid = threadIdx.x;
    const int db  = blockIdx.x & 7;
    const int c   = (blockIdx.x >> 3) & (NCH - 1);
    const int b   = blockIdx.x >> 9;
    const int d   = db * 256 + tid;
    const int t0  = b * L_SZ + c * CS;

    for (int idx = tid; idx < CS * DSTATE; idx += 256) {
        int step = idx >> 4, i = idx & 15;
        Bs[idx] = dbc[(t0 + step) * 96 + DTRANK + i];
    }

    f32x2 A2v[8], Er2[8];
    const float* Ap = A_log + d * DSTATE;
    #pragma unroll
    for (int p = 0; p < 8; p++) {
        A2v[p].x = -1.44269504f * __expf(Ap[2 * p]);
        A2v[p].y = -1.44269504f * __expf(Ap[2 * p + 1]);
        Er2[p].x = 0.0f; Er2[p].y = 0.0f;
    }
    float sd = 0.0f;

    const unsigned short* dp = delta16 + (size_t)t0 * DINNER + d;
    const unsigned short* up = xc16 + (size_t)t0 * DINNER + d;

    float dv[4], uv[4];
    #pragma unroll
    for (int q = 0; q < 4; q++) {
        dv[q] = bf2f(dp[(size_t)q * DINNER]);
        uv[q] = bf2f(up[(size_t)q * DINNER]);
    }
    __syncthreads();

    for (int lo = 0; lo < CS; lo += 4) {
        float nd[4], nu[4];
        if (lo + 4 < CS) {
            #pragma unroll
            for (int q = 0; q < 4; q++) {
                nd[q] = bf2f(dp[(size_t)(lo + 4 + q) * DINNER]);
                nu[q] = bf2f(up[(size_t)(lo + 4 + q) * DINNER]);
            }
        }
        #pragma unroll
        for (int q = 0; q < 4; q++) {
            const float dvq = dv[q];
            const float du  = dvq * uv[q];
            sd += dvq;
            const f32x4* Bv = (const f32x4*)&Bs[(lo + q) * DSTATE];
            f32x4 b0 = Bv[0], b1 = Bv[1], b2 = Bv[2], b3 = Bv[3];
            #define P1PAIR(p, bb) { \
                f32x2 m = dvq * A2v[p]; \
                f32x2 e; e.x = fexp2(m.x); e.y = fexp2(m.y); \
                Er2[p] = e * Er2[p] + du * (bb); }
            P1PAIR(0, b0.xy) P1PAIR(1, b0.zw)
            P1PAIR(2, b1.xy) P1PAIR(3, b1.zw)
            P1PAIR(4, b2.xy) P1PAIR(5, b2.zw)
            P1PAIR(6, b3.xy) P1PAIR(7, b3.zw)
            #undef P1PAIR
        }
        #pragma unroll
        for (int q = 0; q < 4; q++) { dv[q] = nd[q]; uv[q] = nu[q]; }
    }

    sdv[(size_t)(b * NCH + c) * DINNER + d] = sd;
    const long long o = ((long long)((b * NCH + c) * DINNER) + d) * DSTATE;
    Pack8 e0, e1;
    #pragma unroll
    for (int p = 0; p < 4; p++) {
        e0.s[2 * p]     = f2bf(Er2[p].x);
        e0.s[2 * p + 1] = f2bf(Er2[p].y);
        e1.s[2 * p]     = f2bf(Er2[4 + p].x);
        e1.s[2 * p + 1] = f2bf(Er2[4 + p].y);
    }
    *(uint4*)(E + o)     = e0.v;
    *(uint4*)(E + o + 8) = e1.v;
}

// pass2: sequential inter-chunk prefix. p recomputed from sd + A_log.
// E is bf16; running h stays fp32, stored carry snapshots are bf16.
__global__ __launch_bounds__(256) void scan_pass2(
    const float* __restrict__ sdv, const float* __restrict__ A_log,
    unsigned short* __restrict__ E)
{
    const int gid  = blockIdx.x * 256 + threadIdx.x;
    const int b    = gid >> 15;
    const int rest = gid & 32767;
    const int d    = rest >> 4;
    const float A2 = -1.44269504f * __expf(A_log[rest]);
    float h = 0.0f;
    for (int c = 0; c < NCH; c++) {
        const long long idx = (long long)(b * NCH + c) * (DINNER * DSTATE) + rest;
        float p = fexp2(A2 * sdv[(size_t)(b * NCH + c) * DINNER + d]);
        float e = bf2f(E[idx]);
        E[idx] = f2bf(h);
        h = p * h + e;
    }
}

// pass3: bf16 delta + bf16 carry-in, packed math, fused silu(z) gate.
__global__ __launch_bounds__(256) void scan_pass3(
    const unsigned short* __restrict__ xc16, const unsigned short* __restrict__ delta16,
    const float* __restrict__ dbc, const float* __restrict__ A_log,
    const float* __restrict__ D_skip, const unsigned short* __restrict__ Hin,
    const unsigned short* __restrict__ xz16, unsigned short* __restrict__ y16)
{
    __shared__ float BCs[CS * 2 * DSTATE];
    const int tid = threadIdx.x;
    const int db  = blockIdx.x & 7;
    const int c   = (blockIdx.x >> 3) & (NCH - 1);
    const int b   = blockIdx.x >> 9;
    const int d   = db * 256 + tid;
    const int t0  = b * L_SZ + c * CS;

    for (int idx = tid; idx < CS * 2 * DSTATE; idx += 256) {
        int step = idx >> 5, i = idx & 31;
        BCs[idx] = dbc[(t0 + step) * 96 + DTRANK + i];
    }

    f32x2 A2v[8], h2[8];
    const float* Ap = A_log + d * DSTATE;
    const long long o = ((long long)((b * NCH + c) * DINNER) + d) * DSTATE;
    #pragma unroll
    for (int p = 0; p < 8; p++) {
        A2v[p].x = -1.44269504f * __expf(Ap[2 * p]);
        A2v[p].y = -1.44269504f * __expf(Ap[2 * p + 1]);
        h2[p].x = bf2f(Hin[o + 2 * p]);
        h2[p].y = bf2f(Hin[o + 2 * p + 1]);
    }
    const float Dv = D_skip[d];

    const unsigned short* dp = delta16 + (size_t)t0 * DINNER + d;
    const unsigned short* up = xc16 + (size_t)t0 * DINNER + d;
    const unsigned short* zp = xz16 + (size_t)t0 * 4096 + DINNER + d;
    unsigned short* yp = y16 + (size_t)t0 * DINNER + d;

    float dv[4], uv[4], zv[4];
    #pragma unroll
    for (int q = 0; q < 4; q++) {
        dv[q] = bf2f(dp[(size_t)q * DINNER]);
        uv[q] = bf2f(up[(size_t)q * DINNER]);
        zv[q] = bf2f(zp[(size_t)q * 4096]);
    }
    __syncthreads();

    for (int lo = 0; lo < CS; lo += 4) {
        float nd[4], nu[4], nz[4];
        if (lo + 4 < CS) {
            #pragma unroll
            for (int q = 0; q < 4; q++) {
                nd[q] = bf2f(dp[(size_t)(lo + 4 + q) * DINNER]);
                nu[q] = bf2f(up[(size_t)(lo + 4 + q) * DINNER]);
                nz[q] = bf2f(zp[(size_t)(lo + 4 + q) * 4096]);
            }
        }
        #pragma unroll
        for (int q = 0; q < 4; q++) {
            const float dvq = dv[q];
            const float uvq = uv[q];
            const float du  = dvq * uvq;
            const f32x4* Bv = (const f32x4*)&BCs[(lo + q) * 32];
            f32x4 b0 = Bv[0], b1 = Bv[1], b2 = Bv[2], b3 = Bv[3];
            f32x4 c0 = Bv[4], c1 = Bv[5], c2 = Bv[6], c3 = Bv[7];
            f32x2 y0; y0.x = 0.0f; y0.y = 0.0f;
            f32x2 y1; y1.x = 0.0f; y1.y = 0.0f;
            #define P3PAIR(p, bb, cc, ya) { \
                f32x2 m = dvq * A2v[p]; \
                f32x2 e; e.x = fexp2(m.x); e.y = fexp2(m.y); \
                h2[p] = e * h2[p] + du * (bb); \
                ya = ya + h2[p] * (cc); }
            P3PAIR(0, b0.xy, c0.xy, y0) P3PAIR(1, b0.zw, c0.zw, y1)
            P3PAIR(2, b1.xy, c1.xy, y0) P3PAIR(3, b1.zw, c1.zw, y1)
            P3PAIR(4, b2.xy, c2.xy, y0) P3PAIR(5, b2.zw, c2.zw, y1)
            P3PAIR(6, b3.xy, c3.xy, y0) P3PAIR(7, b3.zw, c3.zw, y1)
            #undef P3PAIR
            f32x2 ys = y0 + y1;
            float yv = ys.x + ys.y;
            yp[(size_t)(lo + q) * DINNER] = f2bf((uvq * Dv + yv) * silu_f(zv[q]));
        }
        #pragma unroll
        for (int q = 0; q < 4; q++) { dv[q] = nd[q]; uv[q] = nu[q]; zv[q] = nz[q]; }
    }
}

extern "C" void kernel_launch(void* const* d_in, const int* in_sizes, int n_in,
                              void* d_out, int out_size, void* d_ws, size_t ws_size,
                              hipStream_t stream) {
    const float* x       = (const float*)d_in[0];
    const float* W_in    = (const float*)d_in[1];
    const float* conv_w  = (const float*)d_in[2];
    const float* conv_b  = (const float*)d_in[3];
    const float* W_xproj = (const float*)d_in[4];
    const float* W_dt    = (const float*)d_in[5];
    const float* b_dt    = (const float*)d_in[6];
    const float* A_log   = (const float*)d_in[7];
    const float* D_skip  = (const float*)d_in[8];
    const float* W_out   = (const float*)d_in[9];
    float* out = (float*)d_out;

    // workspace layout, float units. Aliases (dead-before-reuse):
    //   x16 (dead after gemm1)      shares yb16 (written at pass3)
    //   parts6u (GEMM6 bf16 partials, 16.7M ushorts = 8.4M f) spans
    //     [13107200, 21495808) = delta16 + freed gap — delta16 dead after
    //     pass3; disjoint from Ebuf16 at 21495808+. GEMM6 runs after pass3.
    //   Ebuf16 (bf16, 4.2M ushorts = 2.1M f) at [21495808, 23592960).
    //   parts3u (GEMM3 bf16 partials) + sdbuf in [25690112, 27525120).
    float* ws = (float*)d_ws;
    unsigned short* xz16   = (unsigned short*)ws;              // [0 .. 8388608) f
    unsigned short* xc16   = (unsigned short*)(ws +  8388608); // [.. 12582912) f
    float* dbc             = ws + 12582912;                    // [.. 12976128) f
    unsigned short* dtlo16 = (unsigned short*)(ws + 12976128); // [.. 13107200) f
    unsigned short* delta16 = (unsigned short*)(ws + 13107200); // [.. 17301504) f
    unsigned short* parts6u = (unsigned short*)(ws + 13107200); //  alias, [.. 21495808) f
    unsigned short* Ebuf16 = (unsigned short*)(ws + 21495808); // [.. 23592960) f
    unsigned short* parts3u = (unsigned short*)(ws + 25690112); // [.. 27262976) f
    float* sdbuf           = ws + 27262976;                    // [.. 27525120) f : 2*64*2048
    unsigned short* yb16   = (unsigned short*)(ws + 29884416); // [.. 31981568) f
    unsigned short* x16    = yb16;                             //   alias
    unsigned short* W_inT    = (unsigned short*)(ws + 31981568); // [.. 34078720) f
    unsigned short* W_xprojT = (unsigned short*)(ws + 34078720); // [.. 34177024) f
    unsigned short* W_dtT    = (unsigned short*)(ws + 34177024); // [.. 34242560) f
    unsigned short* W_outT   = (unsigned short*)(ws + 34242560); // [.. 35291136) f

    const int MT = 4096;  // B*L tokens

    // 0) all weight transposes + x cast in ONE kernel (8512 blocks)
    prep_all<<<dim3(8512), 256, 0, stream>>>(
        W_in, W_inT, W_xproj, W_xprojT, W_dt, W_dtT, W_out, W_outT, x, x16);

    // 1) xz = x @ W_in              (4096 x 4096, K=1024) -> bf16, 8-phase v3
    gemm_8ph<1><<<dim3(256), 512, 0, stream>>>(
        x16, W_inT, xz16, MT, 4096, 1024, 1024, 4096, 1024);

    // 2) xc16 = silu(causal_dwconv(xin) + b)
    conv_silu_v2<<<dim3(8, 64, 2), 256, 0, stream>>>(xz16, conv_w, conv_b, xc16);

    // 3) dbc = xc @ W_xproj         (4096 x 96, K=2048) — split-K x8, bf16 parts
    gemm_bt_lds<0, 1><<<dim3(1, 32, 8), 256, 0, stream>>>(
        xc16, W_xprojT, parts3u, nullptr, MT, 96, 2048, 2048, 2048, 96, 256);
    reduce_splitk<<<dim3(1536), 256, 0, stream>>>(parts3u, dbc, dtlo16, MT * 96, 8);

    // 4) delta16 = softplus(dt_lo @ W_dt + b_dt)  (4096 x 2048, K=64) -> bf16
    gemm_bt_lds<1, 1><<<dim3(16, 32), 256, 0, stream>>>(
        dtlo16, W_dtT, delta16, b_dt, MT, 2048, 64, 64, 64, 2048, 64);

    // 5) chunked selective scan + fused gate (bf16 y out); bf16 E buffer
    scan_pass1<<<dim3(1024), 256, 0, stream>>>(xc16, delta16, dbc, A_log, sdbuf, Ebuf16);
    scan_pass2<<<dim3(256), 256, 0, stream>>>(sdbuf, A_log, Ebuf16);
    scan_pass3<<<dim3(1024), 256, 0, stream>>>(xc16, delta16, dbc, A_log, D_skip,
                                               Ebuf16, xz16, yb16);

    // 6) out = y @ W_out   (4096 x 1024, K=2048) — 8-phase v3, split-K x4,
    //    bf16 partials (OBF16=2), ldb = 2048 (W_outT row stride = K).
    gemm_8ph<2><<<dim3(64, 1, 4), 512, 0, stream>>>(
        yb16, W_outT, parts6u, MT, 1024, 2048, 2048, 1024, 512);
    reduce4b<<<dim3(2048), 256, 0, stream>>>(parts6u, out, MT * 1024 / 8);
}